// Round 1
// baseline (3119.946 us; speedup 1.0000x reference)
//
#include <hip/hip_runtime.h>

#define N_NODES   100000
#define N_EDGES   1600000
#define DIM       64
#define NUM_GRAPHS 1000

// ---------------------------------------------------------------------------
// Edge kernel: msg = relu(x[src] + ea[e]*We + be); atomicAdd into agg[dst].
// 16 threads per edge, float4 per thread (256B per edge, coalesced per edge).
// ---------------------------------------------------------------------------
__global__ __launch_bounds__(256) void edge_scatter(
    const float* __restrict__ x,     // [N,64]
    const int*   __restrict__ ei,    // [2,E]
    const float* __restrict__ ea,    // [E]
    const float* __restrict__ We,    // [64]
    const float* __restrict__ be,    // [64]
    float*       __restrict__ agg)   // [N,64]
{
    int tid  = blockIdx.x * blockDim.x + threadIdx.x;
    int e    = tid >> 4;
    int part = tid & 15;
    if (e >= N_EDGES) return;

    int   src = ei[e];
    int   dst = ei[N_EDGES + e];
    float a   = ea[e];

    float4 xv = ((const float4*)(x + (size_t)src * DIM))[part];
    float4 w  = ((const float4*)We)[part];
    float4 b  = ((const float4*)be)[part];

    float4 m;
    m.x = fmaxf(fmaf(a, w.x, b.x) + xv.x, 0.f);
    m.y = fmaxf(fmaf(a, w.y, b.y) + xv.y, 0.f);
    m.z = fmaxf(fmaf(a, w.z, b.z) + xv.z, 0.f);
    m.w = fmaxf(fmaf(a, w.w, b.w) + xv.w, 0.f);

    float* p = agg + (size_t)dst * DIM + part * 4;
    atomicAdd(p + 0, m.x);
    atomicAdd(p + 1, m.y);
    atomicAdd(p + 2, m.z);
    atomicAdd(p + 3, m.w);
}

// ---------------------------------------------------------------------------
// Node MLP: out = relu( relu((x+agg)@Wa + ba) @ Wb + bb )
// 4 nodes per 256-thread block (one node per wave); weights staged in LDS.
// If FUSE_POOL, atomically accumulate into pooled[batch[node]] instead.
// ---------------------------------------------------------------------------
template<bool FUSE_POOL>
__global__ __launch_bounds__(256) void node_mlp(
    const float* __restrict__ xin,   // [N,64]
    const float* __restrict__ agg,   // [N,64]
    const float* __restrict__ Wa,    // [64,64] row-major
    const float* __restrict__ ba,    // [64]
    const float* __restrict__ Wb,    // [64,64]
    const float* __restrict__ bb,    // [64]
    float*       __restrict__ out,   // [N,64]  or pooled [G,64]
    const int*   __restrict__ batch) // [N] (only FUSE_POOL)
{
    __shared__ float sWa[64 * 64];
    __shared__ float sWb[64 * 64];
    __shared__ float sy[4][64];
    __shared__ float st[4][64];

    int t = threadIdx.x;
    #pragma unroll
    for (int i = t; i < 64 * 64; i += 256) {
        sWa[i] = Wa[i];
        sWb[i] = Wb[i];
    }

    int nl   = t >> 6;           // node-in-block (== wave id)
    int dim  = t & 63;
    int node = blockIdx.x * 4 + nl;

    float yv = 0.f;
    if (node < N_NODES)
        yv = xin[(size_t)node * DIM + dim] + agg[(size_t)node * DIM + dim];
    sy[nl][dim] = yv;
    __syncthreads();

    float acc = ba[dim];
    #pragma unroll
    for (int k = 0; k < 64; ++k)
        acc = fmaf(sy[nl][k], sWa[k * 64 + dim], acc);
    st[nl][dim] = fmaxf(acc, 0.f);
    __syncthreads();

    float acc2 = bb[dim];
    #pragma unroll
    for (int k = 0; k < 64; ++k)
        acc2 = fmaf(st[nl][k], sWb[k * 64 + dim], acc2);
    float h = fmaxf(acc2, 0.f);

    if (node < N_NODES) {
        if (FUSE_POOL) {
            int g = batch[node];
            atomicAdd(&out[(size_t)g * DIM + dim], h);
        } else {
            out[(size_t)node * DIM + dim] = h;
        }
    }
}

// ---------------------------------------------------------------------------
// Per-graph node counts (batch histogram, as float for the later divide)
// ---------------------------------------------------------------------------
__global__ __launch_bounds__(256) void count_nodes(
    const int* __restrict__ batch, float* __restrict__ cnt)
{
    int i = blockIdx.x * blockDim.x + threadIdx.x;
    if (i < N_NODES) atomicAdd(&cnt[batch[i]], 1.0f);
}

// ---------------------------------------------------------------------------
// Classifier: out[g] = relu(pooled@Wc1 + bc1) @ Wc2 + bc2, pooled = sum/cnt
// One graph per wave, 4 graphs per block.
// ---------------------------------------------------------------------------
__global__ __launch_bounds__(256) void classifier(
    const float* __restrict__ psum,  // [G,64]
    const float* __restrict__ cnt,   // [G]
    const float* __restrict__ Wc1,   // [64,64]
    const float* __restrict__ bc1,   // [64]
    const float* __restrict__ Wc2,   // [64]
    const float* __restrict__ bc2,   // [1]
    float*       __restrict__ out)   // [G]
{
    __shared__ float sW[64 * 64];
    __shared__ float sp[4][64];

    int t = threadIdx.x;
    #pragma unroll
    for (int i = t; i < 64 * 64; i += 256) sW[i] = Wc1[i];

    int nl  = t >> 6;
    int dim = t & 63;
    int g   = blockIdx.x * 4 + nl;

    float pv = 0.f;
    if (g < NUM_GRAPHS) {
        float c = fmaxf(cnt[g], 1.0f);
        pv = psum[(size_t)g * DIM + dim] / c;
    }
    sp[nl][dim] = pv;
    __syncthreads();

    float acc = bc1[dim];
    #pragma unroll
    for (int k = 0; k < 64; ++k)
        acc = fmaf(sp[nl][k], sW[k * 64 + dim], acc);
    float tv = fmaxf(acc, 0.f) * Wc2[dim];

    // wave-64 reduction
    #pragma unroll
    for (int off = 32; off > 0; off >>= 1)
        tv += __shfl_down(tv, off);

    if (dim == 0 && g < NUM_GRAPHS) out[g] = tv + bc2[0];
}

extern "C" void kernel_launch(void* const* d_in, const int* in_sizes, int n_in,
                              void* d_out, int out_size, void* d_ws, size_t ws_size,
                              hipStream_t stream) {
    const float* x     = (const float*)d_in[0];
    const int*   ei    = (const int*)  d_in[1];   // [2,E] int32 (JAX x64 off)
    const float* ea    = (const float*)d_in[2];   // [E,1]
    const int*   batch = (const int*)  d_in[3];   // [N] int32, sorted
    const float* W1a = (const float*)d_in[4];
    const float* b1a = (const float*)d_in[5];
    const float* W1b = (const float*)d_in[6];
    const float* b1b = (const float*)d_in[7];
    const float* We1 = (const float*)d_in[8];
    const float* be1 = (const float*)d_in[9];
    const float* W2a = (const float*)d_in[10];
    const float* b2a = (const float*)d_in[11];
    const float* W2b = (const float*)d_in[12];
    const float* b2b = (const float*)d_in[13];
    const float* We2 = (const float*)d_in[14];
    const float* be2 = (const float*)d_in[15];
    const float* Wc1 = (const float*)d_in[16];
    const float* bc1 = (const float*)d_in[17];
    const float* Wc2 = (const float*)d_in[18];
    const float* bc2 = (const float*)d_in[19];

    float* A      = (float*)d_ws;                       // [N,64] agg scratch
    float* B      = A + (size_t)N_NODES * DIM;          // [N,64] h1
    float* pooled = B + (size_t)N_NODES * DIM;          // [G,64] graph sums
    float* cnt    = pooled + (size_t)NUM_GRAPHS * DIM;  // [G] counts

    const int edge_blocks = (N_EDGES * 16 + 255) / 256;   // 100000
    const int node_blocks = (N_NODES + 3) / 4;            // 25000

    // zero scratch (ws is poisoned 0xAA before every call)
    hipMemsetAsync(A, 0, (size_t)N_NODES * DIM * sizeof(float), stream);
    hipMemsetAsync(pooled, 0, (size_t)(NUM_GRAPHS * DIM + NUM_GRAPHS) * sizeof(float), stream);

    // ---- layer 1 ----
    edge_scatter<<<edge_blocks, 256, 0, stream>>>(x, ei, ea, We1, be1, A);
    node_mlp<false><<<node_blocks, 256, 0, stream>>>(x, A, W1a, b1a, W1b, b1b, B, nullptr);

    // ---- layer 2 (agg buffer reused; stream order guarantees safety) ----
    hipMemsetAsync(A, 0, (size_t)N_NODES * DIM * sizeof(float), stream);
    edge_scatter<<<edge_blocks, 256, 0, stream>>>(B, ei, ea, We2, be2, A);
    node_mlp<true><<<node_blocks, 256, 0, stream>>>(B, A, W2a, b2a, W2b, b2b, pooled, batch);

    // ---- pooling counts + classifier ----
    count_nodes<<<(N_NODES + 255) / 256, 256, 0, stream>>>(batch, cnt);
    classifier<<<(NUM_GRAPHS + 3) / 4, 256, 0, stream>>>(pooled, cnt, Wc1, bc1, Wc2, bc2,
                                                         (float*)d_out);
}

// Round 2
// 1037.182 us; speedup vs baseline: 3.0081x; 3.0081x over previous
//
#include <hip/hip_runtime.h>

#define N_NODES    100000
#define N_EDGES    1600000
#define DIM        64
#define NUM_GRAPHS 1000
#define SCAN_B     256
#define NBLK       ((N_NODES + SCAN_B - 1) / SCAN_B)   // 391

// ---------------------------------------------------------------------------
// CSR build: histogram of dst, exclusive scan -> rowptr, then bucket-fill.
// ---------------------------------------------------------------------------
__global__ __launch_bounds__(256) void deg_hist(
    const int* __restrict__ ei, int* __restrict__ deg)
{
    int e = blockIdx.x * blockDim.x + threadIdx.x;
    if (e < N_EDGES) atomicAdd(&deg[ei[N_EDGES + e]], 1);
}

__global__ __launch_bounds__(SCAN_B) void scan1(
    const int* __restrict__ deg, int* __restrict__ rowptr, int* __restrict__ bsum)
{
    __shared__ int tmp[SCAN_B];
    int t = threadIdx.x;
    int i = blockIdx.x * SCAN_B + t;
    int v = (i < N_NODES) ? deg[i] : 0;
    tmp[t] = v;
    __syncthreads();
    for (int off = 1; off < SCAN_B; off <<= 1) {
        int u = (t >= off) ? tmp[t - off] : 0;
        __syncthreads();
        tmp[t] += u;
        __syncthreads();
    }
    if (i < N_NODES) rowptr[i] = tmp[t] - v;          // exclusive within block
    if (t == SCAN_B - 1) bsum[blockIdx.x] = tmp[t];   // block total
}

__global__ __launch_bounds__(512) void scan2(int* __restrict__ bsum)
{
    __shared__ int tmp[512];
    int t = threadIdx.x;
    int v = (t < NBLK) ? bsum[t] : 0;
    tmp[t] = v;
    __syncthreads();
    for (int off = 1; off < 512; off <<= 1) {
        int u = (t >= off) ? tmp[t - off] : 0;
        __syncthreads();
        tmp[t] += u;
        __syncthreads();
    }
    if (t < NBLK) bsum[t] = tmp[t] - v;               // exclusive block offsets
}

__global__ __launch_bounds__(SCAN_B) void scan3(
    int* __restrict__ rowptr, const int* __restrict__ bsum)
{
    int i = blockIdx.x * SCAN_B + threadIdx.x;
    if (i < N_NODES) rowptr[i] += bsum[blockIdx.x];
    if (i == 0) rowptr[N_NODES] = N_EDGES;
}

__global__ __launch_bounds__(256) void csr_fill(
    const int* __restrict__ ei, const float* __restrict__ ea,
    const int* __restrict__ rowptr, int* __restrict__ cursor,
    int* __restrict__ csr_src, float* __restrict__ csr_a)
{
    int e = blockIdx.x * blockDim.x + threadIdx.x;
    if (e >= N_EDGES) return;
    int dst = ei[N_EDGES + e];
    int pos = rowptr[dst] + atomicAdd(&cursor[dst], 1);
    csr_src[pos] = ei[e];
    csr_a[pos]   = ea[e];
}

// ---------------------------------------------------------------------------
// Fused GINE layer: per node, agg = sum_j relu(x[src_j] + a_j*We + be);
// h = x + agg; out = relu(relu(h@Wa+ba)@Wb+bb).
// One wave per node (lane = dim), 4 nodes/block, grid-stride over nodes.
// Weights staged in LDS once per block. If POOL, scatter h into pooled[g].
// ---------------------------------------------------------------------------
template<bool POOL>
__global__ __launch_bounds__(256) void gine_layer(
    const float* __restrict__ xin,     // [N,64]
    const int*   __restrict__ rowptr,  // [N+1]
    const int*   __restrict__ csr_src, // [E]
    const float* __restrict__ csr_a,   // [E]
    const float* __restrict__ We,      // [64]
    const float* __restrict__ be,      // [64]
    const float* __restrict__ Wa,      // [64,64]
    const float* __restrict__ ba,      // [64]
    const float* __restrict__ Wb,      // [64,64]
    const float* __restrict__ bb,      // [64]
    float*       __restrict__ out,     // [N,64] or pooled [G,64]
    const int*   __restrict__ batch)   // [N] (POOL only)
{
    __shared__ float sWa[64 * 64];
    __shared__ float sWb[64 * 64];
    __shared__ float sy[4][64];
    __shared__ float st[4][64];

    int t = threadIdx.x;
    for (int i = t; i < 64 * 64; i += 256) {
        sWa[i] = Wa[i];
        sWb[i] = Wb[i];
    }
    int nl  = t >> 6;
    int dim = t & 63;
    float wproj = We[dim], bproj = be[dim];
    float bav = ba[dim], bbv = bb[dim];
    __syncthreads();

    for (int base = blockIdx.x * 4; base < N_NODES; base += gridDim.x * 4) {
        int node = base + nl;
        float aggv = 0.f;
        if (node < N_NODES) {
            int beg = rowptr[node], end = rowptr[node + 1];
            // software-pipelined gather: next src/a load decoupled from use
            int   s = (beg < end) ? csr_src[beg] : 0;
            float a = (beg < end) ? csr_a[beg]   : 0.f;
            for (int j = beg; j < end; ++j) {
                int   s2 = 0; float a2 = 0.f;
                if (j + 1 < end) { s2 = csr_src[j + 1]; a2 = csr_a[j + 1]; }
                aggv += fmaxf(xin[(size_t)s * DIM + dim] + fmaf(a, wproj, bproj), 0.f);
                s = s2; a = a2;
            }
            aggv += xin[(size_t)node * DIM + dim];   // h = x + agg (eps=0)
        }
        sy[nl][dim] = aggv;
        __syncthreads();

        float acc = bav;
        #pragma unroll
        for (int k = 0; k < 64; ++k)
            acc = fmaf(sy[nl][k], sWa[k * 64 + dim], acc);
        st[nl][dim] = fmaxf(acc, 0.f);
        __syncthreads();

        float acc2 = bbv;
        #pragma unroll
        for (int k = 0; k < 64; ++k)
            acc2 = fmaf(st[nl][k], sWb[k * 64 + dim], acc2);
        float h = fmaxf(acc2, 0.f);                  // trailing relu (both layers)

        if (node < N_NODES) {
            if (POOL) {
                atomicAdd(&out[(size_t)batch[node] * DIM + dim], h);
            } else {
                out[(size_t)node * DIM + dim] = h;
            }
        }
        __syncthreads();   // protect sy/st reuse next iteration
    }
}

// ---------------------------------------------------------------------------
// Per-graph node counts
// ---------------------------------------------------------------------------
__global__ __launch_bounds__(256) void count_nodes(
    const int* __restrict__ batch, float* __restrict__ cnt)
{
    int i = blockIdx.x * blockDim.x + threadIdx.x;
    if (i < N_NODES) atomicAdd(&cnt[batch[i]], 1.0f);
}

// ---------------------------------------------------------------------------
// Classifier: out[g] = relu((psum/cnt)@Wc1 + bc1) @ Wc2 + bc2
// ---------------------------------------------------------------------------
__global__ __launch_bounds__(256) void classifier(
    const float* __restrict__ psum, const float* __restrict__ cnt,
    const float* __restrict__ Wc1,  const float* __restrict__ bc1,
    const float* __restrict__ Wc2,  const float* __restrict__ bc2,
    float* __restrict__ out)
{
    __shared__ float sW[64 * 64];
    __shared__ float sp[4][64];

    int t = threadIdx.x;
    for (int i = t; i < 64 * 64; i += 256) sW[i] = Wc1[i];

    int nl  = t >> 6;
    int dim = t & 63;
    int g   = blockIdx.x * 4 + nl;

    float pv = 0.f;
    if (g < NUM_GRAPHS) {
        float c = fmaxf(cnt[g], 1.0f);
        pv = psum[(size_t)g * DIM + dim] / c;
    }
    sp[nl][dim] = pv;
    __syncthreads();

    float acc = bc1[dim];
    #pragma unroll
    for (int k = 0; k < 64; ++k)
        acc = fmaf(sp[nl][k], sW[k * 64 + dim], acc);
    float tv = fmaxf(acc, 0.f) * Wc2[dim];

    #pragma unroll
    for (int off = 32; off > 0; off >>= 1)
        tv += __shfl_down(tv, off);

    if (dim == 0 && g < NUM_GRAPHS) out[g] = tv + bc2[0];
}

extern "C" void kernel_launch(void* const* d_in, const int* in_sizes, int n_in,
                              void* d_out, int out_size, void* d_ws, size_t ws_size,
                              hipStream_t stream) {
    const float* x     = (const float*)d_in[0];
    const int*   ei    = (const int*)  d_in[1];
    const float* ea    = (const float*)d_in[2];
    const int*   batch = (const int*)  d_in[3];
    const float* W1a = (const float*)d_in[4];
    const float* b1a = (const float*)d_in[5];
    const float* W1b = (const float*)d_in[6];
    const float* b1b = (const float*)d_in[7];
    const float* We1 = (const float*)d_in[8];
    const float* be1 = (const float*)d_in[9];
    const float* W2a = (const float*)d_in[10];
    const float* b2a = (const float*)d_in[11];
    const float* W2b = (const float*)d_in[12];
    const float* b2b = (const float*)d_in[13];
    const float* We2 = (const float*)d_in[14];
    const float* be2 = (const float*)d_in[15];
    const float* Wc1 = (const float*)d_in[16];
    const float* bc1 = (const float*)d_in[17];
    const float* Wc2 = (const float*)d_in[18];
    const float* bc2 = (const float*)d_in[19];

    // workspace layout (~40 MB)
    int*   deg     = (int*)d_ws;                       // [N]
    int*   cursor  = deg + N_NODES;                    // [N]
    int*   rowptr  = cursor + N_NODES;                 // [N+1]
    int*   bsum    = rowptr + (N_NODES + 1);           // [512]
    int*   csr_src = bsum + 512;                       // [E]
    float* csr_a   = (float*)(csr_src + N_EDGES);      // [E]
    float* B       = csr_a + N_EDGES;                  // [N,64]
    float* pooled  = B + (size_t)N_NODES * DIM;        // [G,64]
    float* cnt     = pooled + (size_t)NUM_GRAPHS * DIM;// [G]

    const int edge_blocks = (N_EDGES + 255) / 256;     // 6250
    const int gine_blocks = 6250;

    // zero: deg+cursor (adjacent), pooled+cnt (adjacent)
    hipMemsetAsync(deg, 0, (size_t)2 * N_NODES * sizeof(int), stream);
    hipMemsetAsync(pooled, 0, (size_t)(NUM_GRAPHS * DIM + NUM_GRAPHS) * sizeof(float), stream);

    // ---- CSR build (shared by both layers) ----
    deg_hist<<<edge_blocks, 256, 0, stream>>>(ei, deg);
    scan1<<<NBLK, SCAN_B, 0, stream>>>(deg, rowptr, bsum);
    scan2<<<1, 512, 0, stream>>>(bsum);
    scan3<<<NBLK, SCAN_B, 0, stream>>>(rowptr, bsum);
    csr_fill<<<edge_blocks, 256, 0, stream>>>(ei, ea, rowptr, cursor, csr_src, csr_a);

    // ---- layer 1: x -> B ----
    gine_layer<false><<<gine_blocks, 256, 0, stream>>>(
        x, rowptr, csr_src, csr_a, We1, be1, W1a, b1a, W1b, b1b, B, nullptr);

    // ---- layer 2: B -> pooled (fused pooling) ----
    gine_layer<true><<<gine_blocks, 256, 0, stream>>>(
        B, rowptr, csr_src, csr_a, We2, be2, W2a, b2a, W2b, b2b, pooled, batch);

    // ---- pooling counts + classifier ----
    count_nodes<<<(N_NODES + 255) / 256, 256, 0, stream>>>(batch, cnt);
    classifier<<<(NUM_GRAPHS + 3) / 4, 256, 0, stream>>>(pooled, cnt, Wc1, bc1, Wc2, bc2,
                                                         (float*)d_out);
}

// Round 3
// 578.812 us; speedup vs baseline: 5.3903x; 1.7919x over previous
//
#include <hip/hip_runtime.h>

#define N_NODES    100000
#define N_EDGES    1600000
#define DIM        64
#define NUM_GRAPHS 1000
#define SCAN_B     256
#define NBLK       ((N_NODES + SCAN_B - 1) / SCAN_B)   // 391

// ---------------------------------------------------------------------------
// CSR build: histogram of dst, exclusive scan -> rowptr, bucket-fill (packed).
// ---------------------------------------------------------------------------
__global__ __launch_bounds__(256) void deg_hist(
    const int* __restrict__ ei, int* __restrict__ deg)
{
    int e = blockIdx.x * blockDim.x + threadIdx.x;
    if (e < N_EDGES) atomicAdd(&deg[ei[N_EDGES + e]], 1);
}

__global__ __launch_bounds__(SCAN_B) void scan1(
    const int* __restrict__ deg, int* __restrict__ rowptr, int* __restrict__ bsum)
{
    __shared__ int tmp[SCAN_B];
    int t = threadIdx.x;
    int i = blockIdx.x * SCAN_B + t;
    int v = (i < N_NODES) ? deg[i] : 0;
    tmp[t] = v;
    __syncthreads();
    for (int off = 1; off < SCAN_B; off <<= 1) {
        int u = (t >= off) ? tmp[t - off] : 0;
        __syncthreads();
        tmp[t] += u;
        __syncthreads();
    }
    if (i < N_NODES) rowptr[i] = tmp[t] - v;
    if (t == SCAN_B - 1) bsum[blockIdx.x] = tmp[t];
}

__global__ __launch_bounds__(512) void scan2(int* __restrict__ bsum)
{
    __shared__ int tmp[512];
    int t = threadIdx.x;
    int v = (t < NBLK) ? bsum[t] : 0;
    tmp[t] = v;
    __syncthreads();
    for (int off = 1; off < 512; off <<= 1) {
        int u = (t >= off) ? tmp[t - off] : 0;
        __syncthreads();
        tmp[t] += u;
        __syncthreads();
    }
    if (t < NBLK) bsum[t] = tmp[t] - v;
}

__global__ __launch_bounds__(SCAN_B) void scan3(
    int* __restrict__ rowptr, const int* __restrict__ bsum)
{
    int i = blockIdx.x * SCAN_B + threadIdx.x;
    if (i < N_NODES) rowptr[i] += bsum[blockIdx.x];
    if (i == 0) rowptr[N_NODES] = N_EDGES;
}

__global__ __launch_bounds__(256) void csr_fill(
    const int* __restrict__ ei, const float* __restrict__ ea,
    const int* __restrict__ rowptr, int* __restrict__ cursor,
    int2* __restrict__ csr_e)
{
    int e = blockIdx.x * blockDim.x + threadIdx.x;
    if (e >= N_EDGES) return;
    int dst = ei[N_EDGES + e];
    int pos = rowptr[dst] + atomicAdd(&cursor[dst], 1);
    csr_e[pos] = make_int2(ei[e], __float_as_int(ea[e]));   // one 8B store
}

// ---------------------------------------------------------------------------
// Fused GINE layer: agg = sum_j relu(x[src_j] + a_j*We + be); h = x + agg;
// out = relu(relu(h@Wa+ba)@Wb+bb).
// 512 threads = 8 waves = 8 nodes per block-iteration; lane = dim.
// Gather unrolled x4 (4 row-loads in flight). Weights staged in LDS once.
// LDS = 36864 B -> 4 blocks/CU -> 32 waves/CU (100% occupancy).
// ---------------------------------------------------------------------------
template<bool POOL>
__global__ __launch_bounds__(512) void gine_layer(
    const float* __restrict__ xin,     // [N,64]
    const int*   __restrict__ rowptr,  // [N+1]
    const int2*  __restrict__ csr_e,   // [E] packed {src, attr_bits}
    const float* __restrict__ We,      // [64]
    const float* __restrict__ be,      // [64]
    const float* __restrict__ Wa,      // [64,64]
    const float* __restrict__ ba,      // [64]
    const float* __restrict__ Wb,      // [64,64]
    const float* __restrict__ bb,      // [64]
    float*       __restrict__ out,     // [N,64] or pooled [G,64]
    const int*   __restrict__ batch)   // [N] (POOL only)
{
    __shared__ float sWa[64 * 64];
    __shared__ float sWb[64 * 64];
    __shared__ float sy[8][64];
    __shared__ float st[8][64];

    int t = threadIdx.x;
    for (int i = t; i < 64 * 64; i += 512) {
        sWa[i] = Wa[i];
        sWb[i] = Wb[i];
    }
    int nl  = t >> 6;          // wave id = node-in-block
    int dim = t & 63;
    float wproj = We[dim], bproj = be[dim];
    float bav = ba[dim], bbv = bb[dim];
    __syncthreads();

    for (int base = blockIdx.x * 8; base < N_NODES; base += gridDim.x * 8) {
        int node = base + nl;
        float aggv = 0.f;
        if (node < N_NODES) {
            int beg = rowptr[node], end = rowptr[node + 1];
            int j = beg;
            // 4 independent row-gathers in flight per wave
            for (; j + 4 <= end; j += 4) {
                int2 p0 = csr_e[j + 0];
                int2 p1 = csr_e[j + 1];
                int2 p2 = csr_e[j + 2];
                int2 p3 = csr_e[j + 3];
                float x0 = xin[(size_t)p0.x * DIM + dim];
                float x1 = xin[(size_t)p1.x * DIM + dim];
                float x2 = xin[(size_t)p2.x * DIM + dim];
                float x3 = xin[(size_t)p3.x * DIM + dim];
                aggv += fmaxf(x0 + fmaf(__int_as_float(p0.y), wproj, bproj), 0.f);
                aggv += fmaxf(x1 + fmaf(__int_as_float(p1.y), wproj, bproj), 0.f);
                aggv += fmaxf(x2 + fmaf(__int_as_float(p2.y), wproj, bproj), 0.f);
                aggv += fmaxf(x3 + fmaf(__int_as_float(p3.y), wproj, bproj), 0.f);
            }
            for (; j < end; ++j) {
                int2 p = csr_e[j];
                aggv += fmaxf(xin[(size_t)p.x * DIM + dim]
                              + fmaf(__int_as_float(p.y), wproj, bproj), 0.f);
            }
            aggv += xin[(size_t)node * DIM + dim];   // h = x + agg (eps=0)
        }
        sy[nl][dim] = aggv;
        __syncthreads();

        float acc = bav;
        #pragma unroll
        for (int k = 0; k < 64; ++k)
            acc = fmaf(sy[nl][k], sWa[k * 64 + dim], acc);
        st[nl][dim] = fmaxf(acc, 0.f);
        __syncthreads();

        float acc2 = bbv;
        #pragma unroll
        for (int k = 0; k < 64; ++k)
            acc2 = fmaf(st[nl][k], sWb[k * 64 + dim], acc2);
        float h = fmaxf(acc2, 0.f);                  // trailing relu (both layers)

        if (node < N_NODES) {
            if (POOL) {
                atomicAdd(&out[(size_t)batch[node] * DIM + dim], h);
            } else {
                out[(size_t)node * DIM + dim] = h;
            }
        }
        __syncthreads();   // protect sy/st before next iteration
    }
}

// ---------------------------------------------------------------------------
// Per-graph node counts
// ---------------------------------------------------------------------------
__global__ __launch_bounds__(256) void count_nodes(
    const int* __restrict__ batch, float* __restrict__ cnt)
{
    int i = blockIdx.x * blockDim.x + threadIdx.x;
    if (i < N_NODES) atomicAdd(&cnt[batch[i]], 1.0f);
}

// ---------------------------------------------------------------------------
// Classifier: out[g] = relu((psum/cnt)@Wc1 + bc1) @ Wc2 + bc2
// ---------------------------------------------------------------------------
__global__ __launch_bounds__(256) void classifier(
    const float* __restrict__ psum, const float* __restrict__ cnt,
    const float* __restrict__ Wc1,  const float* __restrict__ bc1,
    const float* __restrict__ Wc2,  const float* __restrict__ bc2,
    float* __restrict__ out)
{
    __shared__ float sW[64 * 64];
    __shared__ float sp[4][64];

    int t = threadIdx.x;
    for (int i = t; i < 64 * 64; i += 256) sW[i] = Wc1[i];

    int nl  = t >> 6;
    int dim = t & 63;
    int g   = blockIdx.x * 4 + nl;

    float pv = 0.f;
    if (g < NUM_GRAPHS) {
        float c = fmaxf(cnt[g], 1.0f);
        pv = psum[(size_t)g * DIM + dim] / c;
    }
    sp[nl][dim] = pv;
    __syncthreads();

    float acc = bc1[dim];
    #pragma unroll
    for (int k = 0; k < 64; ++k)
        acc = fmaf(sp[nl][k], sW[k * 64 + dim], acc);
    float tv = fmaxf(acc, 0.f) * Wc2[dim];

    #pragma unroll
    for (int off = 32; off > 0; off >>= 1)
        tv += __shfl_down(tv, off);

    if (dim == 0 && g < NUM_GRAPHS) out[g] = tv + bc2[0];
}

extern "C" void kernel_launch(void* const* d_in, const int* in_sizes, int n_in,
                              void* d_out, int out_size, void* d_ws, size_t ws_size,
                              hipStream_t stream) {
    const float* x     = (const float*)d_in[0];
    const int*   ei    = (const int*)  d_in[1];
    const float* ea    = (const float*)d_in[2];
    const int*   batch = (const int*)  d_in[3];
    const float* W1a = (const float*)d_in[4];
    const float* b1a = (const float*)d_in[5];
    const float* W1b = (const float*)d_in[6];
    const float* b1b = (const float*)d_in[7];
    const float* We1 = (const float*)d_in[8];
    const float* be1 = (const float*)d_in[9];
    const float* W2a = (const float*)d_in[10];
    const float* b2a = (const float*)d_in[11];
    const float* W2b = (const float*)d_in[12];
    const float* b2b = (const float*)d_in[13];
    const float* We2 = (const float*)d_in[14];
    const float* be2 = (const float*)d_in[15];
    const float* Wc1 = (const float*)d_in[16];
    const float* bc1 = (const float*)d_in[17];
    const float* Wc2 = (const float*)d_in[18];
    const float* bc2 = (const float*)d_in[19];

    // workspace layout
    int*   deg     = (int*)d_ws;                       // [N]
    int*   cursor  = deg + N_NODES;                    // [N]
    int*   rowptr  = cursor + N_NODES;                 // [N+1]
    int*   bsum    = rowptr + (N_NODES + 1);           // [512]
    int2*  csr_e   = (int2*)(bsum + 512);              // [E] packed
    float* B       = (float*)(csr_e + N_EDGES);        // [N,64]
    float* pooled  = B + (size_t)N_NODES * DIM;        // [G,64]
    float* cnt     = pooled + (size_t)NUM_GRAPHS * DIM;// [G]

    const int edge_blocks = (N_EDGES + 255) / 256;     // 6250
    const int gine_blocks = 1024;                      // 4 blocks/CU, grid-stride

    hipMemsetAsync(deg, 0, (size_t)2 * N_NODES * sizeof(int), stream);
    hipMemsetAsync(pooled, 0, (size_t)(NUM_GRAPHS * DIM + NUM_GRAPHS) * sizeof(float), stream);

    // ---- CSR build (shared by both layers) ----
    deg_hist<<<edge_blocks, 256, 0, stream>>>(ei, deg);
    scan1<<<NBLK, SCAN_B, 0, stream>>>(deg, rowptr, bsum);
    scan2<<<1, 512, 0, stream>>>(bsum);
    scan3<<<NBLK, SCAN_B, 0, stream>>>(rowptr, bsum);
    csr_fill<<<edge_blocks, 256, 0, stream>>>(ei, ea, rowptr, cursor, csr_e);

    // ---- layer 1: x -> B ----
    gine_layer<false><<<gine_blocks, 512, 0, stream>>>(
        x, rowptr, csr_e, We1, be1, W1a, b1a, W1b, b1b, B, nullptr);

    // ---- layer 2: B -> pooled (fused pooling) ----
    gine_layer<true><<<gine_blocks, 512, 0, stream>>>(
        B, rowptr, csr_e, We2, be2, W2a, b2a, W2b, b2b, pooled, batch);

    // ---- pooling counts + classifier ----
    count_nodes<<<(N_NODES + 255) / 256, 256, 0, stream>>>(batch, cnt);
    classifier<<<(NUM_GRAPHS + 3) / 4, 256, 0, stream>>>(pooled, cnt, Wc1, bc1, Wc2, bc2,
                                                         (float*)d_out);
}

// Round 4
// 516.951 us; speedup vs baseline: 6.0353x; 1.1197x over previous
//
#include <hip/hip_runtime.h>

#define N_NODES    100000
#define N_EDGES    1600000
#define DIM        64
#define NUM_GRAPHS 1000
#define SCAN_B     256
#define NBLK       ((N_NODES + SCAN_B - 1) / SCAN_B)   // 391
#define HIST_BLK   1563    // ceil((N_EDGES/4)/256)
#define CONV_BLK   3125    // (N_NODES*DIM/8)/256 exactly

// bf16 helpers (manual, round-to-nearest-even)
__device__ __forceinline__ unsigned short f2bf(float f) {
    unsigned int b = __float_as_uint(f);
    b += 0x7FFFu + ((b >> 16) & 1u);
    return (unsigned short)(b >> 16);
}
__device__ __forceinline__ float bf2f(unsigned short u) {
    return __uint_as_float(((unsigned int)u) << 16);
}

// ---------------------------------------------------------------------------
// Fused: dst-degree histogram (4 edges/thread) + x -> bf16 table conversion.
// ---------------------------------------------------------------------------
__global__ __launch_bounds__(256) void prep(
    const int* __restrict__ ei, const float* __restrict__ x,
    int* __restrict__ deg, unsigned short* __restrict__ x16)
{
    int b = blockIdx.x;
    if (b < HIST_BLK) {
        int e4 = (b * 256 + threadIdx.x) * 4;
        if (e4 < N_EDGES) {
            int4 d = *(const int4*)(ei + N_EDGES + e4);
            atomicAdd(&deg[d.x], 1);
            atomicAdd(&deg[d.y], 1);
            atomicAdd(&deg[d.z], 1);
            atomicAdd(&deg[d.w], 1);
        }
    } else {
        int t = (b - HIST_BLK) * 256 + threadIdx.x;       // 0..799999
        if (t < N_NODES * DIM / 8) {
            int base = t * 8;
            float4 f0 = *(const float4*)(x + base);
            float4 f1 = *(const float4*)(x + base + 4);
            uint4 o;
            o.x = (unsigned)f2bf(f0.x) | ((unsigned)f2bf(f0.y) << 16);
            o.y = (unsigned)f2bf(f0.z) | ((unsigned)f2bf(f0.w) << 16);
            o.z = (unsigned)f2bf(f1.x) | ((unsigned)f2bf(f1.y) << 16);
            o.w = (unsigned)f2bf(f1.z) | ((unsigned)f2bf(f1.w) << 16);
            *(uint4*)(x16 + base) = o;
        }
    }
}

// ---------------------------------------------------------------------------
// Exclusive scan of deg -> rowptr (3 small kernels)
// ---------------------------------------------------------------------------
__global__ __launch_bounds__(SCAN_B) void scan1(
    const int* __restrict__ deg, int* __restrict__ rowptr, int* __restrict__ bsum)
{
    __shared__ int tmp[SCAN_B];
    int t = threadIdx.x;
    int i = blockIdx.x * SCAN_B + t;
    int v = (i < N_NODES) ? deg[i] : 0;
    tmp[t] = v;
    __syncthreads();
    for (int off = 1; off < SCAN_B; off <<= 1) {
        int u = (t >= off) ? tmp[t - off] : 0;
        __syncthreads();
        tmp[t] += u;
        __syncthreads();
    }
    if (i < N_NODES) rowptr[i] = tmp[t] - v;
    if (t == SCAN_B - 1) bsum[blockIdx.x] = tmp[t];
}

__global__ __launch_bounds__(512) void scan2(int* __restrict__ bsum)
{
    __shared__ int tmp[512];
    int t = threadIdx.x;
    int v = (t < NBLK) ? bsum[t] : 0;
    tmp[t] = v;
    __syncthreads();
    for (int off = 1; off < 512; off <<= 1) {
        int u = (t >= off) ? tmp[t - off] : 0;
        __syncthreads();
        tmp[t] += u;
        __syncthreads();
    }
    if (t < NBLK) bsum[t] = tmp[t] - v;
}

__global__ __launch_bounds__(SCAN_B) void scan3(
    int* __restrict__ rowptr, const int* __restrict__ bsum)
{
    int i = blockIdx.x * SCAN_B + threadIdx.x;
    if (i < N_NODES) rowptr[i] += bsum[blockIdx.x];
    if (i == 0) rowptr[N_NODES] = N_EDGES;
}

// ---------------------------------------------------------------------------
// CSR fill, 2 edges/thread, packed {src, attr_bits}
// ---------------------------------------------------------------------------
__global__ __launch_bounds__(256) void csr_fill(
    const int* __restrict__ ei, const float* __restrict__ ea,
    const int* __restrict__ rowptr, int* __restrict__ cursor,
    int2* __restrict__ csr_e)
{
    int e2 = (blockIdx.x * blockDim.x + threadIdx.x) * 2;
    if (e2 >= N_EDGES) return;
    int2   s = *(const int2*)(ei + e2);
    int2   d = *(const int2*)(ei + N_EDGES + e2);
    float2 a = *(const float2*)(ea + e2);
    int p0 = rowptr[d.x] + atomicAdd(&cursor[d.x], 1);
    csr_e[p0] = make_int2(s.x, __float_as_int(a.x));
    int p1 = rowptr[d.y] + atomicAdd(&cursor[d.y], 1);
    csr_e[p1] = make_int2(s.y, __float_as_int(a.y));
}

// ---------------------------------------------------------------------------
// Fused GINE layer, bf16 gather table.
// agg = sum_j relu(gtab[src_j] + a_j*We + be); h = self + agg;
// out = relu(relu(h@Wa+ba)@Wb+bb), written bf16 (OUT16) or fp32.
// 512 thr = 8 waves = 8 nodes/iter; lane = dim; gather unrolled x8.
// LDS 36864 B -> 4 blocks/CU -> 32 waves/CU.
// ---------------------------------------------------------------------------
template<bool SELF32, bool OUT16>
__global__ __launch_bounds__(512, 8) void gine16(
    const unsigned short* __restrict__ gtab,   // [N,64] bf16
    const float*          __restrict__ self32, // [N,64] fp32 (SELF32 only)
    const int*            __restrict__ rowptr,
    const int2*           __restrict__ csr_e,
    const float* __restrict__ We, const float* __restrict__ be,
    const float* __restrict__ Wa, const float* __restrict__ ba,
    const float* __restrict__ Wb, const float* __restrict__ bb,
    float*          __restrict__ out32,
    unsigned short* __restrict__ out16)
{
    __shared__ float sWa[64 * 64];
    __shared__ float sWb[64 * 64];
    __shared__ float sy[8][64];
    __shared__ float st[8][64];

    int t = threadIdx.x;
    for (int i = t; i < 64 * 64; i += 512) {
        sWa[i] = Wa[i];
        sWb[i] = Wb[i];
    }
    int nl  = t >> 6;
    int dim = t & 63;
    float wproj = We[dim], bproj = be[dim];
    float bav = ba[dim], bbv = bb[dim];
    __syncthreads();

    for (int base = blockIdx.x * 8; base < N_NODES; base += gridDim.x * 8) {
        int node = base + nl;
        float aggv = 0.f;
        if (node < N_NODES) {
            int beg = rowptr[node], end = rowptr[node + 1];
            int j = beg;
            for (; j + 8 <= end; j += 8) {
                int2 p0 = csr_e[j + 0], p1 = csr_e[j + 1];
                int2 p2 = csr_e[j + 2], p3 = csr_e[j + 3];
                int2 p4 = csr_e[j + 4], p5 = csr_e[j + 5];
                int2 p6 = csr_e[j + 6], p7 = csr_e[j + 7];
                float g0 = bf2f(gtab[(size_t)p0.x * DIM + dim]);
                float g1 = bf2f(gtab[(size_t)p1.x * DIM + dim]);
                float g2 = bf2f(gtab[(size_t)p2.x * DIM + dim]);
                float g3 = bf2f(gtab[(size_t)p3.x * DIM + dim]);
                float g4 = bf2f(gtab[(size_t)p4.x * DIM + dim]);
                float g5 = bf2f(gtab[(size_t)p5.x * DIM + dim]);
                float g6 = bf2f(gtab[(size_t)p6.x * DIM + dim]);
                float g7 = bf2f(gtab[(size_t)p7.x * DIM + dim]);
                aggv += fmaxf(g0 + fmaf(__int_as_float(p0.y), wproj, bproj), 0.f);
                aggv += fmaxf(g1 + fmaf(__int_as_float(p1.y), wproj, bproj), 0.f);
                aggv += fmaxf(g2 + fmaf(__int_as_float(p2.y), wproj, bproj), 0.f);
                aggv += fmaxf(g3 + fmaf(__int_as_float(p3.y), wproj, bproj), 0.f);
                aggv += fmaxf(g4 + fmaf(__int_as_float(p4.y), wproj, bproj), 0.f);
                aggv += fmaxf(g5 + fmaf(__int_as_float(p5.y), wproj, bproj), 0.f);
                aggv += fmaxf(g6 + fmaf(__int_as_float(p6.y), wproj, bproj), 0.f);
                aggv += fmaxf(g7 + fmaf(__int_as_float(p7.y), wproj, bproj), 0.f);
            }
            for (; j + 4 <= end; j += 4) {
                int2 p0 = csr_e[j + 0], p1 = csr_e[j + 1];
                int2 p2 = csr_e[j + 2], p3 = csr_e[j + 3];
                float g0 = bf2f(gtab[(size_t)p0.x * DIM + dim]);
                float g1 = bf2f(gtab[(size_t)p1.x * DIM + dim]);
                float g2 = bf2f(gtab[(size_t)p2.x * DIM + dim]);
                float g3 = bf2f(gtab[(size_t)p3.x * DIM + dim]);
                aggv += fmaxf(g0 + fmaf(__int_as_float(p0.y), wproj, bproj), 0.f);
                aggv += fmaxf(g1 + fmaf(__int_as_float(p1.y), wproj, bproj), 0.f);
                aggv += fmaxf(g2 + fmaf(__int_as_float(p2.y), wproj, bproj), 0.f);
                aggv += fmaxf(g3 + fmaf(__int_as_float(p3.y), wproj, bproj), 0.f);
            }
            for (; j < end; ++j) {
                int2 p = csr_e[j];
                aggv += fmaxf(bf2f(gtab[(size_t)p.x * DIM + dim])
                              + fmaf(__int_as_float(p.y), wproj, bproj), 0.f);
            }
            // self term (eps = 0)
            if (SELF32) aggv += self32[(size_t)node * DIM + dim];
            else        aggv += bf2f(gtab[(size_t)node * DIM + dim]);
        }
        sy[nl][dim] = aggv;
        __syncthreads();

        float acc = bav;
        #pragma unroll
        for (int k = 0; k < 64; ++k)
            acc = fmaf(sy[nl][k], sWa[k * 64 + dim], acc);
        st[nl][dim] = fmaxf(acc, 0.f);
        __syncthreads();

        float acc2 = bbv;
        #pragma unroll
        for (int k = 0; k < 64; ++k)
            acc2 = fmaf(st[nl][k], sWb[k * 64 + dim], acc2);
        float h = fmaxf(acc2, 0.f);                  // trailing relu

        if (node < N_NODES) {
            if (OUT16) out16[(size_t)node * DIM + dim] = f2bf(h);
            else       out32[(size_t)node * DIM + dim] = h;
        }
        __syncthreads();
    }
}

// ---------------------------------------------------------------------------
// Segment mean over sorted batch: pooled[g] = mean(B2[rows of graph g]).
// One wave per graph; boundaries via binary search (batch sorted).
// ---------------------------------------------------------------------------
__device__ __forceinline__ int lbound(const int* __restrict__ a, int key) {
    int lo = 0, hi = N_NODES;
    while (lo < hi) {
        int mid = (lo + hi) >> 1;
        if (a[mid] < key) lo = mid + 1; else hi = mid;
    }
    return lo;
}

__global__ __launch_bounds__(256) void segmean(
    const float* __restrict__ B2, const int* __restrict__ batch,
    float* __restrict__ pooled)
{
    int g   = blockIdx.x * 4 + (threadIdx.x >> 6);
    int dim = threadIdx.x & 63;
    if (g >= NUM_GRAPHS) return;
    int s = lbound(batch, g);
    int e = lbound(batch, g + 1);
    float sum = 0.f;
    int i = s;
    for (; i + 4 <= e; i += 4) {
        float v0 = B2[(size_t)(i + 0) * DIM + dim];
        float v1 = B2[(size_t)(i + 1) * DIM + dim];
        float v2 = B2[(size_t)(i + 2) * DIM + dim];
        float v3 = B2[(size_t)(i + 3) * DIM + dim];
        sum += v0 + v1 + v2 + v3;
    }
    for (; i < e; ++i) sum += B2[(size_t)i * DIM + dim];
    pooled[(size_t)g * DIM + dim] = sum / (float)max(e - s, 1);
}

// ---------------------------------------------------------------------------
// Classifier: out[g] = relu(pooled@Wc1 + bc1) @ Wc2 + bc2
// ---------------------------------------------------------------------------
__global__ __launch_bounds__(256) void classifier(
    const float* __restrict__ pooled,
    const float* __restrict__ Wc1,  const float* __restrict__ bc1,
    const float* __restrict__ Wc2,  const float* __restrict__ bc2,
    float* __restrict__ out)
{
    __shared__ float sW[64 * 64];
    __shared__ float sp[4][64];

    int t = threadIdx.x;
    for (int i = t; i < 64 * 64; i += 256) sW[i] = Wc1[i];

    int nl  = t >> 6;
    int dim = t & 63;
    int g   = blockIdx.x * 4 + nl;

    sp[nl][dim] = (g < NUM_GRAPHS) ? pooled[(size_t)g * DIM + dim] : 0.f;
    __syncthreads();

    float acc = bc1[dim];
    #pragma unroll
    for (int k = 0; k < 64; ++k)
        acc = fmaf(sp[nl][k], sW[k * 64 + dim], acc);
    float tv = fmaxf(acc, 0.f) * Wc2[dim];

    #pragma unroll
    for (int off = 32; off > 0; off >>= 1)
        tv += __shfl_down(tv, off);

    if (dim == 0 && g < NUM_GRAPHS) out[g] = tv + bc2[0];
}

extern "C" void kernel_launch(void* const* d_in, const int* in_sizes, int n_in,
                              void* d_out, int out_size, void* d_ws, size_t ws_size,
                              hipStream_t stream) {
    const float* x     = (const float*)d_in[0];
    const int*   ei    = (const int*)  d_in[1];
    const float* ea    = (const float*)d_in[2];
    const int*   batch = (const int*)  d_in[3];
    const float* W1a = (const float*)d_in[4];
    const float* b1a = (const float*)d_in[5];
    const float* W1b = (const float*)d_in[6];
    const float* b1b = (const float*)d_in[7];
    const float* We1 = (const float*)d_in[8];
    const float* be1 = (const float*)d_in[9];
    const float* W2a = (const float*)d_in[10];
    const float* b2a = (const float*)d_in[11];
    const float* W2b = (const float*)d_in[12];
    const float* b2b = (const float*)d_in[13];
    const float* We2 = (const float*)d_in[14];
    const float* be2 = (const float*)d_in[15];
    const float* Wc1 = (const float*)d_in[16];
    const float* bc1 = (const float*)d_in[17];
    const float* Wc2 = (const float*)d_in[18];
    const float* bc2 = (const float*)d_in[19];

    // workspace layout (big 16B-aligned arrays first), ~66 MB
    int2*           csr_e  = (int2*)d_ws;                            // [E]
    unsigned short* x16    = (unsigned short*)(csr_e + N_EDGES);     // [N*64]
    unsigned short* B16    = x16 + (size_t)N_NODES * DIM;            // [N*64]
    float*          B2     = (float*)(B16 + (size_t)N_NODES * DIM);  // [N,64]
    float*          pooled = B2 + (size_t)N_NODES * DIM;             // [G,64]
    int*            deg    = (int*)(pooled + (size_t)NUM_GRAPHS * DIM);
    int*            cursor = deg + N_NODES;
    int*            rowptr = cursor + N_NODES;                       // [N+2]
    int*            bsum   = rowptr + (N_NODES + 2);                 // [512]

    hipMemsetAsync(deg, 0, (size_t)2 * N_NODES * sizeof(int), stream);

    // ---- CSR build + bf16 table ----
    prep<<<HIST_BLK + CONV_BLK, 256, 0, stream>>>(ei, x, deg, x16);
    scan1<<<NBLK, SCAN_B, 0, stream>>>(deg, rowptr, bsum);
    scan2<<<1, 512, 0, stream>>>(bsum);
    scan3<<<NBLK, SCAN_B, 0, stream>>>(rowptr, bsum);
    csr_fill<<<(N_EDGES / 2 + 255) / 256, 256, 0, stream>>>(ei, ea, rowptr, cursor, csr_e);

    // ---- layer 1: gather x16, self fp32 x -> B16 (bf16) ----
    gine16<true, true><<<1024, 512, 0, stream>>>(
        x16, x, rowptr, csr_e, We1, be1, W1a, b1a, W1b, b1b, nullptr, B16);

    // ---- layer 2: gather B16, self B16 -> B2 (fp32) ----
    gine16<false, false><<<1024, 512, 0, stream>>>(
        B16, nullptr, rowptr, csr_e, We2, be2, W2a, b2a, W2b, b2b, B2, nullptr);

    // ---- pooling + classifier ----
    segmean<<<(NUM_GRAPHS + 3) / 4, 256, 0, stream>>>(B2, batch, pooled);
    classifier<<<(NUM_GRAPHS + 3) / 4, 256, 0, stream>>>(pooled, Wc1, bc1, Wc2, bc2,
                                                         (float*)d_out);
}

// Round 5
// 487.800 us; speedup vs baseline: 6.3960x; 1.0598x over previous
//
#include <hip/hip_runtime.h>

#define N_NODES    100000
#define N_EDGES    1600000
#define DIM        64
#define NUM_GRAPHS 1000
#define SCAN_B     256
#define NBLK       ((N_NODES + SCAN_B - 1) / SCAN_B)   // 391
#define HIST_BLK   1563    // ceil((N_EDGES/4)/256)
#define CONV_BLK   3125    // (N_NODES*DIM/8)/256 exactly

// bf16 helpers (manual, round-to-nearest-even)
__device__ __forceinline__ unsigned short f2bf(float f) {
    unsigned int b = __float_as_uint(f);
    b += 0x7FFFu + ((b >> 16) & 1u);
    return (unsigned short)(b >> 16);
}

// ---------------------------------------------------------------------------
// Fused: dst-degree histogram (4 edges/thread) + x -> bf16 table conversion.
// ---------------------------------------------------------------------------
__global__ __launch_bounds__(256) void prep(
    const int* __restrict__ ei, const float* __restrict__ x,
    int* __restrict__ deg, unsigned short* __restrict__ x16)
{
    int b = blockIdx.x;
    if (b < HIST_BLK) {
        int e4 = (b * 256 + threadIdx.x) * 4;
        if (e4 < N_EDGES) {
            int4 d = *(const int4*)(ei + N_EDGES + e4);
            atomicAdd(&deg[d.x], 1);
            atomicAdd(&deg[d.y], 1);
            atomicAdd(&deg[d.z], 1);
            atomicAdd(&deg[d.w], 1);
        }
    } else {
        int t = (b - HIST_BLK) * 256 + threadIdx.x;       // 0..799999
        if (t < N_NODES * DIM / 8) {
            int base = t * 8;
            float4 f0 = *(const float4*)(x + base);
            float4 f1 = *(const float4*)(x + base + 4);
            uint4 o;
            o.x = (unsigned)f2bf(f0.x) | ((unsigned)f2bf(f0.y) << 16);
            o.y = (unsigned)f2bf(f0.z) | ((unsigned)f2bf(f0.w) << 16);
            o.z = (unsigned)f2bf(f1.x) | ((unsigned)f2bf(f1.y) << 16);
            o.w = (unsigned)f2bf(f1.z) | ((unsigned)f2bf(f1.w) << 16);
            *(uint4*)(x16 + base) = o;
        }
    }
}

// ---------------------------------------------------------------------------
// Exclusive scan of deg -> rowptr
// ---------------------------------------------------------------------------
__global__ __launch_bounds__(SCAN_B) void scan1(
    const int* __restrict__ deg, int* __restrict__ rowptr, int* __restrict__ bsum)
{
    __shared__ int tmp[SCAN_B];
    int t = threadIdx.x;
    int i = blockIdx.x * SCAN_B + t;
    int v = (i < N_NODES) ? deg[i] : 0;
    tmp[t] = v;
    __syncthreads();
    for (int off = 1; off < SCAN_B; off <<= 1) {
        int u = (t >= off) ? tmp[t - off] : 0;
        __syncthreads();
        tmp[t] += u;
        __syncthreads();
    }
    if (i < N_NODES) rowptr[i] = tmp[t] - v;
    if (t == SCAN_B - 1) bsum[blockIdx.x] = tmp[t];
}

__global__ __launch_bounds__(512) void scan2(int* __restrict__ bsum)
{
    __shared__ int tmp[512];
    int t = threadIdx.x;
    int v = (t < NBLK) ? bsum[t] : 0;
    tmp[t] = v;
    __syncthreads();
    for (int off = 1; off < 512; off <<= 1) {
        int u = (t >= off) ? tmp[t - off] : 0;
        __syncthreads();
        tmp[t] += u;
        __syncthreads();
    }
    if (t < NBLK) bsum[t] = tmp[t] - v;
}

__global__ __launch_bounds__(SCAN_B) void scan3(
    int* __restrict__ rowptr, const int* __restrict__ bsum)
{
    int i = blockIdx.x * SCAN_B + threadIdx.x;
    if (i < N_NODES) rowptr[i] += bsum[blockIdx.x];
    if (i == 0) rowptr[N_NODES] = N_EDGES;
}

// ---------------------------------------------------------------------------
// CSR fill, 2 edges/thread, packed {src*32 (uint index into bf16x2 table), attr}
// ---------------------------------------------------------------------------
__global__ __launch_bounds__(256) void csr_fill(
    const int* __restrict__ ei, const float* __restrict__ ea,
    const int* __restrict__ rowptr, int* __restrict__ cursor,
    int2* __restrict__ csr_e)
{
    int e2 = (blockIdx.x * blockDim.x + threadIdx.x) * 2;
    if (e2 >= N_EDGES) return;
    int2   s = *(const int2*)(ei + e2);
    int2   d = *(const int2*)(ei + N_EDGES + e2);
    float2 a = *(const float2*)(ea + e2);
    int p0 = rowptr[d.x] + atomicAdd(&cursor[d.x], 1);
    csr_e[p0] = make_int2(s.x << 5, __float_as_int(a.x));
    int p1 = rowptr[d.y] + atomicAdd(&cursor[d.y], 1);
    csr_e[p1] = make_int2(s.y << 5, __float_as_int(a.y));
}

// ---------------------------------------------------------------------------
// Fused GINE layer, dim-pair layout: half-wave (32 lanes) = 1 node,
// lane = 2 adjacent dims (bf16x2 / float2). 512 thr = 16 nodes/iter.
// Gather: one dword load per lane fetches 2 dims; one wave instruction
// covers 2 nodes' rows. MLP: float2 weight reads (upper half broadcasts),
// float4 y reads -> 4x fewer LDS instructions than lane-per-dim.
// LDS 40960 B -> 4 blocks/CU -> 32 waves/CU.
// ---------------------------------------------------------------------------
template<bool SELF32, bool OUT16>
__global__ __launch_bounds__(512, 8) void gine16(
    const unsigned int* __restrict__ g32,    // [N*32] bf16x2 gather table
    const float*        __restrict__ self32, // [N,64] fp32 self (SELF32)
    const int*          __restrict__ rowptr,
    const int2*         __restrict__ csr_e,  // {src*32, attr_bits}
    const float* __restrict__ We, const float* __restrict__ be,
    const float* __restrict__ Wa, const float* __restrict__ ba,
    const float* __restrict__ Wb, const float* __restrict__ bb,
    float*        __restrict__ out32,
    unsigned int* __restrict__ out16)        // bf16x2 rows
{
    __shared__ float sWa[64 * 64];
    __shared__ float sWb[64 * 64];
    __shared__ float sy[16][64];
    __shared__ float st[16][64];

    int t = threadIdx.x;
    for (int i = t; i < 64 * 64; i += 512) {
        sWa[i] = Wa[i];
        sWb[i] = Wb[i];
    }
    int half = t >> 5;           // node slot 0..15
    int p    = t & 31;           // dim pair
    int dim0 = p * 2;
    float2 wp  = make_float2(We[dim0], We[dim0 + 1]);
    float2 bp  = make_float2(be[dim0], be[dim0 + 1]);
    float2 ba2 = make_float2(ba[dim0], ba[dim0 + 1]);
    float2 bb2 = make_float2(bb[dim0], bb[dim0 + 1]);
    __syncthreads();

    for (int base = blockIdx.x * 16; base < N_NODES; base += gridDim.x * 16) {
        int  node  = base + half;
        bool valid = node < N_NODES;
        int beg = 0, deg = 0;
        if (valid) { beg = rowptr[node]; deg = rowptr[node + 1] - beg; }
        int degmax = max(deg, __shfl_xor(deg, 32));

        float2 agg = make_float2(0.f, 0.f);
        for (int j = 0; j < degmax; j += 4) {
            bool a0 = (j + 0) < deg, a1 = (j + 1) < deg;
            bool a2 = (j + 2) < deg, a3 = (j + 3) < deg;
            int2 r0 = csr_e[beg + (a0 ? j + 0 : 0)];
            int2 r1 = csr_e[beg + (a1 ? j + 1 : 0)];
            int2 r2 = csr_e[beg + (a2 ? j + 2 : 0)];
            int2 r3 = csr_e[beg + (a3 ? j + 3 : 0)];
            unsigned int u0 = g32[r0.x + p];
            unsigned int u1 = g32[r1.x + p];
            unsigned int u2 = g32[r2.x + p];
            unsigned int u3 = g32[r3.x + p];
            {
                float s = a0 ? 1.f : 0.f, av = __int_as_float(r0.y);
                float lo = __uint_as_float(u0 << 16);
                float hi = __uint_as_float(u0 & 0xFFFF0000u);
                agg.x = fmaf(s, fmaxf(lo + fmaf(av, wp.x, bp.x), 0.f), agg.x);
                agg.y = fmaf(s, fmaxf(hi + fmaf(av, wp.y, bp.y), 0.f), agg.y);
            }
            {
                float s = a1 ? 1.f : 0.f, av = __int_as_float(r1.y);
                float lo = __uint_as_float(u1 << 16);
                float hi = __uint_as_float(u1 & 0xFFFF0000u);
                agg.x = fmaf(s, fmaxf(lo + fmaf(av, wp.x, bp.x), 0.f), agg.x);
                agg.y = fmaf(s, fmaxf(hi + fmaf(av, wp.y, bp.y), 0.f), agg.y);
            }
            {
                float s = a2 ? 1.f : 0.f, av = __int_as_float(r2.y);
                float lo = __uint_as_float(u2 << 16);
                float hi = __uint_as_float(u2 & 0xFFFF0000u);
                agg.x = fmaf(s, fmaxf(lo + fmaf(av, wp.x, bp.x), 0.f), agg.x);
                agg.y = fmaf(s, fmaxf(hi + fmaf(av, wp.y, bp.y), 0.f), agg.y);
            }
            {
                float s = a3 ? 1.f : 0.f, av = __int_as_float(r3.y);
                float lo = __uint_as_float(u3 << 16);
                float hi = __uint_as_float(u3 & 0xFFFF0000u);
                agg.x = fmaf(s, fmaxf(lo + fmaf(av, wp.x, bp.x), 0.f), agg.x);
                agg.y = fmaf(s, fmaxf(hi + fmaf(av, wp.y, bp.y), 0.f), agg.y);
            }
        }
        if (valid) {   // self term (eps = 0)
            if (SELF32) {
                float2 sv = *(const float2*)(self32 + (size_t)node * DIM + dim0);
                agg.x += sv.x;
                agg.y += sv.y;
            } else {
                unsigned int u = g32[node * 32 + p];
                agg.x += __uint_as_float(u << 16);
                agg.y += __uint_as_float(u & 0xFFFF0000u);
            }
        }
        *(float2*)&sy[half][dim0] = agg;
        __syncthreads();

        float2 acc = ba2;
        #pragma unroll
        for (int k = 0; k < 64; k += 4) {
            float4 y = *(const float4*)&sy[half][k];
            const float* w = &sWa[k * 64 + dim0];
            float2 w0 = *(const float2*)(w);
            float2 w1 = *(const float2*)(w + 64);
            float2 w2 = *(const float2*)(w + 128);
            float2 w3 = *(const float2*)(w + 192);
            acc.x = fmaf(y.x, w0.x, acc.x); acc.y = fmaf(y.x, w0.y, acc.y);
            acc.x = fmaf(y.y, w1.x, acc.x); acc.y = fmaf(y.y, w1.y, acc.y);
            acc.x = fmaf(y.z, w2.x, acc.x); acc.y = fmaf(y.z, w2.y, acc.y);
            acc.x = fmaf(y.w, w3.x, acc.x); acc.y = fmaf(y.w, w3.y, acc.y);
        }
        *(float2*)&st[half][dim0] = make_float2(fmaxf(acc.x, 0.f), fmaxf(acc.y, 0.f));
        __syncthreads();

        float2 acc2 = bb2;
        #pragma unroll
        for (int k = 0; k < 64; k += 4) {
            float4 y = *(const float4*)&st[half][k];
            const float* w = &sWb[k * 64 + dim0];
            float2 w0 = *(const float2*)(w);
            float2 w1 = *(const float2*)(w + 64);
            float2 w2 = *(const float2*)(w + 128);
            float2 w3 = *(const float2*)(w + 192);
            acc2.x = fmaf(y.x, w0.x, acc2.x); acc2.y = fmaf(y.x, w0.y, acc2.y);
            acc2.x = fmaf(y.y, w1.x, acc2.x); acc2.y = fmaf(y.y, w1.y, acc2.y);
            acc2.x = fmaf(y.z, w2.x, acc2.x); acc2.y = fmaf(y.z, w2.y, acc2.y);
            acc2.x = fmaf(y.w, w3.x, acc2.x); acc2.y = fmaf(y.w, w3.y, acc2.y);
        }
        float2 h = make_float2(fmaxf(acc2.x, 0.f), fmaxf(acc2.y, 0.f));

        if (valid) {
            if (OUT16) {
                out16[(size_t)node * 32 + p] =
                    (unsigned)f2bf(h.x) | ((unsigned)f2bf(h.y) << 16);
            } else {
                *(float2*)(out32 + (size_t)node * DIM + dim0) = h;
            }
        }
        __syncthreads();
    }
}

// ---------------------------------------------------------------------------
// Segment mean over sorted batch; one wave per graph.
// ---------------------------------------------------------------------------
__device__ __forceinline__ int lbound(const int* __restrict__ a, int key) {
    int lo = 0, hi = N_NODES;
    while (lo < hi) {
        int mid = (lo + hi) >> 1;
        if (a[mid] < key) lo = mid + 1; else hi = mid;
    }
    return lo;
}

__global__ __launch_bounds__(256) void segmean(
    const float* __restrict__ B2, const int* __restrict__ batch,
    float* __restrict__ pooled)
{
    int g   = blockIdx.x * 4 + (threadIdx.x >> 6);
    int dim = threadIdx.x & 63;
    if (g >= NUM_GRAPHS) return;
    int s = lbound(batch, g);
    int e = lbound(batch, g + 1);
    float sum = 0.f;
    int i = s;
    for (; i + 4 <= e; i += 4) {
        float v0 = B2[(size_t)(i + 0) * DIM + dim];
        float v1 = B2[(size_t)(i + 1) * DIM + dim];
        float v2 = B2[(size_t)(i + 2) * DIM + dim];
        float v3 = B2[(size_t)(i + 3) * DIM + dim];
        sum += v0 + v1 + v2 + v3;
    }
    for (; i < e; ++i) sum += B2[(size_t)i * DIM + dim];
    pooled[(size_t)g * DIM + dim] = sum / (float)max(e - s, 1);
}

// ---------------------------------------------------------------------------
// Classifier: out[g] = relu(pooled@Wc1 + bc1) @ Wc2 + bc2
// ---------------------------------------------------------------------------
__global__ __launch_bounds__(256) void classifier(
    const float* __restrict__ pooled,
    const float* __restrict__ Wc1,  const float* __restrict__ bc1,
    const float* __restrict__ Wc2,  const float* __restrict__ bc2,
    float* __restrict__ out)
{
    __shared__ float sW[64 * 64];
    __shared__ float sp[4][64];

    int t = threadIdx.x;
    for (int i = t; i < 64 * 64; i += 256) sW[i] = Wc1[i];

    int nl  = t >> 6;
    int dim = t & 63;
    int g   = blockIdx.x * 4 + nl;

    sp[nl][dim] = (g < NUM_GRAPHS) ? pooled[(size_t)g * DIM + dim] : 0.f;
    __syncthreads();

    float acc = bc1[dim];
    #pragma unroll
    for (int k = 0; k < 64; ++k)
        acc = fmaf(sp[nl][k], sW[k * 64 + dim], acc);
    float tv = fmaxf(acc, 0.f) * Wc2[dim];

    #pragma unroll
    for (int off = 32; off > 0; off >>= 1)
        tv += __shfl_down(tv, off);

    if (dim == 0 && g < NUM_GRAPHS) out[g] = tv + bc2[0];
}

extern "C" void kernel_launch(void* const* d_in, const int* in_sizes, int n_in,
                              void* d_out, int out_size, void* d_ws, size_t ws_size,
                              hipStream_t stream) {
    const float* x     = (const float*)d_in[0];
    const int*   ei    = (const int*)  d_in[1];
    const float* ea    = (const float*)d_in[2];
    const int*   batch = (const int*)  d_in[3];
    const float* W1a = (const float*)d_in[4];
    const float* b1a = (const float*)d_in[5];
    const float* W1b = (const float*)d_in[6];
    const float* b1b = (const float*)d_in[7];
    const float* We1 = (const float*)d_in[8];
    const float* be1 = (const float*)d_in[9];
    const float* W2a = (const float*)d_in[10];
    const float* b2a = (const float*)d_in[11];
    const float* W2b = (const float*)d_in[12];
    const float* b2b = (const float*)d_in[13];
    const float* We2 = (const float*)d_in[14];
    const float* be2 = (const float*)d_in[15];
    const float* Wc1 = (const float*)d_in[16];
    const float* bc1 = (const float*)d_in[17];
    const float* Wc2 = (const float*)d_in[18];
    const float* bc2 = (const float*)d_in[19];

    // workspace layout (big 16B-aligned arrays first)
    int2*           csr_e  = (int2*)d_ws;                            // [E]
    unsigned short* x16    = (unsigned short*)(csr_e + N_EDGES);     // [N*64]
    unsigned short* B16    = x16 + (size_t)N_NODES * DIM;            // [N*64]
    float*          B2     = (float*)(B16 + (size_t)N_NODES * DIM);  // [N,64]
    float*          pooled = B2 + (size_t)N_NODES * DIM;             // [G,64]
    int*            deg    = (int*)(pooled + (size_t)NUM_GRAPHS * DIM);
    int*            cursor = deg + N_NODES;
    int*            rowptr = cursor + N_NODES;                       // [N+2]
    int*            bsum   = rowptr + (N_NODES + 2);                 // [512]

    hipMemsetAsync(deg, 0, (size_t)2 * N_NODES * sizeof(int), stream);

    // ---- CSR build + bf16 table ----
    prep<<<HIST_BLK + CONV_BLK, 256, 0, stream>>>(ei, x, deg, x16);
    scan1<<<NBLK, SCAN_B, 0, stream>>>(deg, rowptr, bsum);
    scan2<<<1, 512, 0, stream>>>(bsum);
    scan3<<<NBLK, SCAN_B, 0, stream>>>(rowptr, bsum);
    csr_fill<<<(N_EDGES / 2 + 255) / 256, 256, 0, stream>>>(ei, ea, rowptr, cursor, csr_e);

    // ---- layer 1: gather x16, self fp32 x -> B16 (bf16) ----
    gine16<true, true><<<1024, 512, 0, stream>>>(
        (const unsigned int*)x16, x, rowptr, csr_e,
        We1, be1, W1a, b1a, W1b, b1b, nullptr, (unsigned int*)B16);

    // ---- layer 2: gather B16 -> B2 (fp32) ----
    gine16<false, false><<<1024, 512, 0, stream>>>(
        (const unsigned int*)B16, nullptr, rowptr, csr_e,
        We2, be2, W2a, b2a, W2b, b2b, B2, nullptr);

    // ---- pooling + classifier ----
    segmean<<<(NUM_GRAPHS + 3) / 4, 256, 0, stream>>>(B2, batch, pooled);
    classifier<<<(NUM_GRAPHS + 3) / 4, 256, 0, stream>>>(pooled, Wc1, bc1, Wc2, bc2,
                                                         (float*)d_out);
}

// Round 6
// 456.763 us; speedup vs baseline: 6.8306x; 1.0680x over previous
//
#include <hip/hip_runtime.h>

#define N_NODES    100000
#define N_EDGES    1600000
#define DIM        64
#define NUM_GRAPHS 1000
#define SCAN_B     256
#define NBLK       ((N_NODES + SCAN_B - 1) / SCAN_B)   // 391
#define HIST_BLK   1563    // ceil((N_EDGES/4)/256)
#define CONV_BLK   3125    // (N_NODES*DIM/8)/256 exactly
#define FILL_SLICE 6400    // 256 slices x 6400 = 1,638,400 >= N_EDGES
#define NODES_PER_XCD (N_NODES / 8)   // 12500

// bf16 helpers (manual, round-to-nearest-even)
__device__ __forceinline__ unsigned short f2bf(float f) {
    unsigned int b = __float_as_uint(f);
    b += 0x7FFFu + ((b >> 16) & 1u);
    return (unsigned short)(b >> 16);
}

// ---------------------------------------------------------------------------
// Fused: dst-degree histogram (4 edges/thread) + x -> bf16 table conversion.
// ---------------------------------------------------------------------------
__global__ __launch_bounds__(256) void prep(
    const int* __restrict__ ei, const float* __restrict__ x,
    int* __restrict__ deg, unsigned short* __restrict__ x16)
{
    int b = blockIdx.x;
    if (b < HIST_BLK) {
        int e4 = (b * 256 + threadIdx.x) * 4;
        if (e4 < N_EDGES) {
            int4 d = *(const int4*)(ei + N_EDGES + e4);
            atomicAdd(&deg[d.x], 1);
            atomicAdd(&deg[d.y], 1);
            atomicAdd(&deg[d.z], 1);
            atomicAdd(&deg[d.w], 1);
        }
    } else {
        int t = (b - HIST_BLK) * 256 + threadIdx.x;       // 0..799999
        if (t < N_NODES * DIM / 8) {
            int base = t * 8;
            float4 f0 = *(const float4*)(x + base);
            float4 f1 = *(const float4*)(x + base + 4);
            uint4 o;
            o.x = (unsigned)f2bf(f0.x) | ((unsigned)f2bf(f0.y) << 16);
            o.y = (unsigned)f2bf(f0.z) | ((unsigned)f2bf(f0.w) << 16);
            o.z = (unsigned)f2bf(f1.x) | ((unsigned)f2bf(f1.y) << 16);
            o.w = (unsigned)f2bf(f1.z) | ((unsigned)f2bf(f1.w) << 16);
            *(uint4*)(x16 + base) = o;
        }
    }
}

// ---------------------------------------------------------------------------
// Scan: block-local exclusive scan (scan1), then per-block prefix fold (scan23)
// ---------------------------------------------------------------------------
__global__ __launch_bounds__(SCAN_B) void scan1(
    const int* __restrict__ deg, int* __restrict__ rowptr, int* __restrict__ bsum)
{
    __shared__ int tmp[SCAN_B];
    int t = threadIdx.x;
    int i = blockIdx.x * SCAN_B + t;
    int v = (i < N_NODES) ? deg[i] : 0;
    tmp[t] = v;
    __syncthreads();
    for (int off = 1; off < SCAN_B; off <<= 1) {
        int u = (t >= off) ? tmp[t - off] : 0;
        __syncthreads();
        tmp[t] += u;
        __syncthreads();
    }
    if (i < N_NODES) rowptr[i] = tmp[t] - v;
    if (t == SCAN_B - 1) bsum[blockIdx.x] = tmp[t];
}

__global__ __launch_bounds__(SCAN_B) void scan23(
    int* __restrict__ rowptr, const int* __restrict__ bsum)
{
    __shared__ int red[SCAN_B];
    int t = threadIdx.x;
    int sum = 0;
    for (int i = t; i < blockIdx.x; i += SCAN_B) sum += bsum[i];
    red[t] = sum;
    __syncthreads();
    for (int off = SCAN_B / 2; off > 0; off >>= 1) {
        if (t < off) red[t] += red[t + off];
        __syncthreads();
    }
    int prefix = red[0];
    int i = blockIdx.x * SCAN_B + t;
    if (i < N_NODES) rowptr[i] += prefix;
    if (i == 0) rowptr[N_NODES] = N_EDGES;
}

// ---------------------------------------------------------------------------
// CSR fill, XCD-partitioned by dst range to kill cross-XCD partial-line
// write amplification. owner = blockIdx & 7 (round-robin block->XCD
// heuristic: all writes to one csr_e region then come from one XCD whose
// 1.6 MB region is L2-resident). Correct regardless of actual mapping.
// 2048 blocks = 256 slices x 8 owners; slice's dst[] re-read 8x from L2/L3.
// ---------------------------------------------------------------------------
__global__ __launch_bounds__(256) void csr_fill(
    const int* __restrict__ ei, const float* __restrict__ ea,
    const int* __restrict__ rowptr, int* __restrict__ cursor,
    int2* __restrict__ csr_e)
{
    int owner = blockIdx.x & 7;
    int slice = blockIdx.x >> 3;                 // 0..255
    int lo = owner * NODES_PER_XCD;
    int hi = lo + NODES_PER_XCD;
    int base = slice * FILL_SLICE;
    int stop = min(base + FILL_SLICE, N_EDGES);
    for (int e = base + threadIdx.x * 4; e < stop; e += 256 * 4) {
        int4 d = *(const int4*)(ei + N_EDGES + e);   // N_EDGES % 4 == 0
        if (d.x >= lo && d.x < hi) {
            int p = rowptr[d.x] + atomicAdd(&cursor[d.x], 1);
            csr_e[p] = make_int2(ei[e + 0] << 5, __float_as_int(ea[e + 0]));
        }
        if (d.y >= lo && d.y < hi) {
            int p = rowptr[d.y] + atomicAdd(&cursor[d.y], 1);
            csr_e[p] = make_int2(ei[e + 1] << 5, __float_as_int(ea[e + 1]));
        }
        if (d.z >= lo && d.z < hi) {
            int p = rowptr[d.z] + atomicAdd(&cursor[d.z], 1);
            csr_e[p] = make_int2(ei[e + 2] << 5, __float_as_int(ea[e + 2]));
        }
        if (d.w >= lo && d.w < hi) {
            int p = rowptr[d.w] + atomicAdd(&cursor[d.w], 1);
            csr_e[p] = make_int2(ei[e + 3] << 5, __float_as_int(ea[e + 3]));
        }
    }
}

// ---------------------------------------------------------------------------
// Fused GINE layer, dim-pair layout: half-wave (32 lanes) = 1 node,
// lane = 2 adjacent dims (bf16x2 / float2). 512 thr = 16 nodes/iter.
// Gather unrolled x8 (8 rows in flight). MLP: float2 weight reads,
// float4 y reads. LDS 40960 B -> 4 blocks/CU -> 32 waves/CU.
// ---------------------------------------------------------------------------
template<bool SELF32, bool OUT16>
__global__ __launch_bounds__(512, 8) void gine16(
    const unsigned int* __restrict__ g32,    // [N*32] bf16x2 gather table
    const float*        __restrict__ self32, // [N,64] fp32 self (SELF32)
    const int*          __restrict__ rowptr,
    const int2*         __restrict__ csr_e,  // {src*32, attr_bits}
    const float* __restrict__ We, const float* __restrict__ be,
    const float* __restrict__ Wa, const float* __restrict__ ba,
    const float* __restrict__ Wb, const float* __restrict__ bb,
    float*        __restrict__ out32,
    unsigned int* __restrict__ out16)        // bf16x2 rows
{
    __shared__ float sWa[64 * 64];
    __shared__ float sWb[64 * 64];
    __shared__ float sy[16][64];
    __shared__ float st[16][64];

    int t = threadIdx.x;
    for (int i = t; i < 64 * 64; i += 512) {
        sWa[i] = Wa[i];
        sWb[i] = Wb[i];
    }
    int half = t >> 5;           // node slot 0..15
    int p    = t & 31;           // dim pair
    int dim0 = p * 2;
    float2 wp  = make_float2(We[dim0], We[dim0 + 1]);
    float2 bp  = make_float2(be[dim0], be[dim0 + 1]);
    float2 ba2 = make_float2(ba[dim0], ba[dim0 + 1]);
    float2 bb2 = make_float2(bb[dim0], bb[dim0 + 1]);
    __syncthreads();

    for (int base = blockIdx.x * 16; base < N_NODES; base += gridDim.x * 16) {
        int  node  = base + half;
        bool valid = node < N_NODES;
        int beg = 0, deg = 0;
        if (valid) { beg = rowptr[node]; deg = rowptr[node + 1] - beg; }
        int degmax = max(deg, __shfl_xor(deg, 32));

        float2 agg = make_float2(0.f, 0.f);
        int j = 0;
        for (; j + 8 <= degmax; j += 8) {
            int2 r0 = csr_e[beg + ((j + 0) < deg ? j + 0 : 0)];
            int2 r1 = csr_e[beg + ((j + 1) < deg ? j + 1 : 0)];
            int2 r2 = csr_e[beg + ((j + 2) < deg ? j + 2 : 0)];
            int2 r3 = csr_e[beg + ((j + 3) < deg ? j + 3 : 0)];
            int2 r4 = csr_e[beg + ((j + 4) < deg ? j + 4 : 0)];
            int2 r5 = csr_e[beg + ((j + 5) < deg ? j + 5 : 0)];
            int2 r6 = csr_e[beg + ((j + 6) < deg ? j + 6 : 0)];
            int2 r7 = csr_e[beg + ((j + 7) < deg ? j + 7 : 0)];
            unsigned int u0 = g32[r0.x + p];
            unsigned int u1 = g32[r1.x + p];
            unsigned int u2 = g32[r2.x + p];
            unsigned int u3 = g32[r3.x + p];
            unsigned int u4 = g32[r4.x + p];
            unsigned int u5 = g32[r5.x + p];
            unsigned int u6 = g32[r6.x + p];
            unsigned int u7 = g32[r7.x + p];
            #define EDGE_ACC(rr, uu, cond)                                          \
            {                                                                       \
                float s = (cond) ? 1.f : 0.f, av = __int_as_float(rr.y);            \
                float elo = __uint_as_float(uu << 16);                              \
                float ehi = __uint_as_float(uu & 0xFFFF0000u);                      \
                agg.x = fmaf(s, fmaxf(elo + fmaf(av, wp.x, bp.x), 0.f), agg.x);     \
                agg.y = fmaf(s, fmaxf(ehi + fmaf(av, wp.y, bp.y), 0.f), agg.y);     \
            }
            EDGE_ACC(r0, u0, (j + 0) < deg)
            EDGE_ACC(r1, u1, (j + 1) < deg)
            EDGE_ACC(r2, u2, (j + 2) < deg)
            EDGE_ACC(r3, u3, (j + 3) < deg)
            EDGE_ACC(r4, u4, (j + 4) < deg)
            EDGE_ACC(r5, u5, (j + 5) < deg)
            EDGE_ACC(r6, u6, (j + 6) < deg)
            EDGE_ACC(r7, u7, (j + 7) < deg)
        }
        for (; j < degmax; j += 4) {
            int2 r0 = csr_e[beg + ((j + 0) < deg ? j + 0 : 0)];
            int2 r1 = csr_e[beg + ((j + 1) < deg ? j + 1 : 0)];
            int2 r2 = csr_e[beg + ((j + 2) < deg ? j + 2 : 0)];
            int2 r3 = csr_e[beg + ((j + 3) < deg ? j + 3 : 0)];
            unsigned int u0 = g32[r0.x + p];
            unsigned int u1 = g32[r1.x + p];
            unsigned int u2 = g32[r2.x + p];
            unsigned int u3 = g32[r3.x + p];
            EDGE_ACC(r0, u0, (j + 0) < deg)
            EDGE_ACC(r1, u1, (j + 1) < deg)
            EDGE_ACC(r2, u2, (j + 2) < deg)
            EDGE_ACC(r3, u3, (j + 3) < deg)
            #undef EDGE_ACC
        }
        if (valid) {   // self term (eps = 0)
            if (SELF32) {
                float2 sv = *(const float2*)(self32 + (size_t)node * DIM + dim0);
                agg.x += sv.x;
                agg.y += sv.y;
            } else {
                unsigned int u = g32[node * 32 + p];
                agg.x += __uint_as_float(u << 16);
                agg.y += __uint_as_float(u & 0xFFFF0000u);
            }
        }
        *(float2*)&sy[half][dim0] = agg;
        __syncthreads();

        float2 acc = ba2;
        #pragma unroll
        for (int k = 0; k < 64; k += 4) {
            float4 y = *(const float4*)&sy[half][k];
            const float* w = &sWa[k * 64 + dim0];
            float2 w0 = *(const float2*)(w);
            float2 w1 = *(const float2*)(w + 64);
            float2 w2 = *(const float2*)(w + 128);
            float2 w3 = *(const float2*)(w + 192);
            acc.x = fmaf(y.x, w0.x, acc.x); acc.y = fmaf(y.x, w0.y, acc.y);
            acc.x = fmaf(y.y, w1.x, acc.x); acc.y = fmaf(y.y, w1.y, acc.y);
            acc.x = fmaf(y.z, w2.x, acc.x); acc.y = fmaf(y.z, w2.y, acc.y);
            acc.x = fmaf(y.w, w3.x, acc.x); acc.y = fmaf(y.w, w3.y, acc.y);
        }
        *(float2*)&st[half][dim0] = make_float2(fmaxf(acc.x, 0.f), fmaxf(acc.y, 0.f));
        __syncthreads();

        float2 acc2 = bb2;
        #pragma unroll
        for (int k = 0; k < 64; k += 4) {
            float4 y = *(const float4*)&st[half][k];
            const float* w = &sWb[k * 64 + dim0];
            float2 w0 = *(const float2*)(w);
            float2 w1 = *(const float2*)(w + 64);
            float2 w2 = *(const float2*)(w + 128);
            float2 w3 = *(const float2*)(w + 192);
            acc2.x = fmaf(y.x, w0.x, acc2.x); acc2.y = fmaf(y.x, w0.y, acc2.y);
            acc2.x = fmaf(y.y, w1.x, acc2.x); acc2.y = fmaf(y.y, w1.y, acc2.y);
            acc2.x = fmaf(y.z, w2.x, acc2.x); acc2.y = fmaf(y.z, w2.y, acc2.y);
            acc2.x = fmaf(y.w, w3.x, acc2.x); acc2.y = fmaf(y.w, w3.y, acc2.y);
        }
        float2 h = make_float2(fmaxf(acc2.x, 0.f), fmaxf(acc2.y, 0.f));

        if (valid) {
            if (OUT16) {
                out16[(size_t)node * 32 + p] =
                    (unsigned)f2bf(h.x) | ((unsigned)f2bf(h.y) << 16);
            } else {
                *(float2*)(out32 + (size_t)node * DIM + dim0) = h;
            }
        }
        __syncthreads();
    }
}

// ---------------------------------------------------------------------------
// Segment mean over sorted batch; one wave per graph.
// ---------------------------------------------------------------------------
__device__ __forceinline__ int lbound(const int* __restrict__ a, int key) {
    int lo = 0, hi = N_NODES;
    while (lo < hi) {
        int mid = (lo + hi) >> 1;
        if (a[mid] < key) lo = mid + 1; else hi = mid;
    }
    return lo;
}

__global__ __launch_bounds__(256) void segmean(
    const float* __restrict__ B2, const int* __restrict__ batch,
    float* __restrict__ pooled)
{
    int g   = blockIdx.x * 4 + (threadIdx.x >> 6);
    int dim = threadIdx.x & 63;
    if (g >= NUM_GRAPHS) return;
    int s = lbound(batch, g);
    int e = lbound(batch, g + 1);
    float sum = 0.f;
    int i = s;
    for (; i + 4 <= e; i += 4) {
        float v0 = B2[(size_t)(i + 0) * DIM + dim];
        float v1 = B2[(size_t)(i + 1) * DIM + dim];
        float v2 = B2[(size_t)(i + 2) * DIM + dim];
        float v3 = B2[(size_t)(i + 3) * DIM + dim];
        sum += v0 + v1 + v2 + v3;
    }
    for (; i < e; ++i) sum += B2[(size_t)i * DIM + dim];
    pooled[(size_t)g * DIM + dim] = sum / (float)max(e - s, 1);
}

// ---------------------------------------------------------------------------
// Classifier: out[g] = relu(pooled@Wc1 + bc1) @ Wc2 + bc2
// ---------------------------------------------------------------------------
__global__ __launch_bounds__(256) void classifier(
    const float* __restrict__ pooled,
    const float* __restrict__ Wc1,  const float* __restrict__ bc1,
    const float* __restrict__ Wc2,  const float* __restrict__ bc2,
    float* __restrict__ out)
{
    __shared__ float sW[64 * 64];
    __shared__ float sp[4][64];

    int t = threadIdx.x;
    for (int i = t; i < 64 * 64; i += 256) sW[i] = Wc1[i];

    int nl  = t >> 6;
    int dim = t & 63;
    int g   = blockIdx.x * 4 + nl;

    sp[nl][dim] = (g < NUM_GRAPHS) ? pooled[(size_t)g * DIM + dim] : 0.f;
    __syncthreads();

    float acc = bc1[dim];
    #pragma unroll
    for (int k = 0; k < 64; ++k)
        acc = fmaf(sp[nl][k], sW[k * 64 + dim], acc);
    float tv = fmaxf(acc, 0.f) * Wc2[dim];

    #pragma unroll
    for (int off = 32; off > 0; off >>= 1)
        tv += __shfl_down(tv, off);

    if (dim == 0 && g < NUM_GRAPHS) out[g] = tv + bc2[0];
}

extern "C" void kernel_launch(void* const* d_in, const int* in_sizes, int n_in,
                              void* d_out, int out_size, void* d_ws, size_t ws_size,
                              hipStream_t stream) {
    const float* x     = (const float*)d_in[0];
    const int*   ei    = (const int*)  d_in[1];
    const float* ea    = (const float*)d_in[2];
    const int*   batch = (const int*)  d_in[3];
    const float* W1a = (const float*)d_in[4];
    const float* b1a = (const float*)d_in[5];
    const float* W1b = (const float*)d_in[6];
    const float* b1b = (const float*)d_in[7];
    const float* We1 = (const float*)d_in[8];
    const float* be1 = (const float*)d_in[9];
    const float* W2a = (const float*)d_in[10];
    const float* b2a = (const float*)d_in[11];
    const float* W2b = (const float*)d_in[12];
    const float* b2b = (const float*)d_in[13];
    const float* We2 = (const float*)d_in[14];
    const float* be2 = (const float*)d_in[15];
    const float* Wc1 = (const float*)d_in[16];
    const float* bc1 = (const float*)d_in[17];
    const float* Wc2 = (const float*)d_in[18];
    const float* bc2 = (const float*)d_in[19];

    // workspace layout (big 16B-aligned arrays first)
    int2*           csr_e  = (int2*)d_ws;                            // [E]
    unsigned short* x16    = (unsigned short*)(csr_e + N_EDGES);     // [N*64]
    unsigned short* B16    = x16 + (size_t)N_NODES * DIM;            // [N*64]
    float*          B2     = (float*)(B16 + (size_t)N_NODES * DIM);  // [N,64]
    float*          pooled = B2 + (size_t)N_NODES * DIM;             // [G,64]
    int*            deg    = (int*)(pooled + (size_t)NUM_GRAPHS * DIM);
    int*            cursor = deg + N_NODES;
    int*            rowptr = cursor + N_NODES;                       // [N+2]
    int*            bsum   = rowptr + (N_NODES + 2);                 // [512]

    hipMemsetAsync(deg, 0, (size_t)2 * N_NODES * sizeof(int), stream);

    // ---- CSR build + bf16 table ----
    prep<<<HIST_BLK + CONV_BLK, 256, 0, stream>>>(ei, x, deg, x16);
    scan1<<<NBLK, SCAN_B, 0, stream>>>(deg, rowptr, bsum);
    scan23<<<NBLK, SCAN_B, 0, stream>>>(rowptr, bsum);
    csr_fill<<<2048, 256, 0, stream>>>(ei, ea, rowptr, cursor, csr_e);

    // ---- layer 1: gather x16, self fp32 x -> B16 (bf16) ----
    gine16<true, true><<<1024, 512, 0, stream>>>(
        (const unsigned int*)x16, x, rowptr, csr_e,
        We1, be1, W1a, b1a, W1b, b1b, nullptr, (unsigned int*)B16);

    // ---- layer 2: gather B16 -> B2 (fp32) ----
    gine16<false, false><<<1024, 512, 0, stream>>>(
        (const unsigned int*)B16, nullptr, rowptr, csr_e,
        We2, be2, W2a, b2a, W2b, b2b, B2, nullptr);

    // ---- pooling + classifier ----
    segmean<<<(NUM_GRAPHS + 3) / 4, 256, 0, stream>>>(B2, batch, pooled);
    classifier<<<(NUM_GRAPHS + 3) / 4, 256, 0, stream>>>(pooled, Wc1, bc1, Wc2, bc2,
                                                         (float*)d_out);
}

// Round 7
// 386.544 us; speedup vs baseline: 8.0714x; 1.1817x over previous
//
#include <hip/hip_runtime.h>

#define N_NODES    100000
#define N_EDGES    1600000
#define DIM        64
#define NUM_GRAPHS 1000
#define SCAN_B     256
#define NBLK       ((N_NODES + SCAN_B - 1) / SCAN_B)   // 391
#define HIST_BLK   1563    // ceil((N_EDGES/4)/256)
#define CONV_BLK   3125    // (N_NODES*DIM/8)/256 exactly
#define FILL_SLICE 6400    // 256 slices x 6400 >= N_EDGES
#define NODES_PER_XCD (N_NODES / 8)   // 12500
#define PAD        72      // padded LDS row length in bf16 units (breaks bank conflicts)

typedef __attribute__((ext_vector_type(8))) short bf16x8;
typedef __attribute__((ext_vector_type(4))) float f32x4;

// bf16 helpers (round-to-nearest-even)
__device__ __forceinline__ unsigned short f2bf(float f) {
    unsigned int b = __float_as_uint(f);
    b += 0x7FFFu + ((b >> 16) & 1u);
    return (unsigned short)(b >> 16);
}

// ---------------------------------------------------------------------------
// Fused: dst-degree histogram (4 edges/thread) + x -> bf16 table conversion.
// ---------------------------------------------------------------------------
__global__ __launch_bounds__(256) void prep(
    const int* __restrict__ ei, const float* __restrict__ x,
    int* __restrict__ deg, unsigned short* __restrict__ x16)
{
    int b = blockIdx.x;
    if (b < HIST_BLK) {
        int e4 = (b * 256 + threadIdx.x) * 4;
        if (e4 < N_EDGES) {
            int4 d = *(const int4*)(ei + N_EDGES + e4);
            atomicAdd(&deg[d.x], 1);
            atomicAdd(&deg[d.y], 1);
            atomicAdd(&deg[d.z], 1);
            atomicAdd(&deg[d.w], 1);
        }
    } else {
        int t = (b - HIST_BLK) * 256 + threadIdx.x;
        if (t < N_NODES * DIM / 8) {
            int base = t * 8;
            float4 f0 = *(const float4*)(x + base);
            float4 f1 = *(const float4*)(x + base + 4);
            uint4 o;
            o.x = (unsigned)f2bf(f0.x) | ((unsigned)f2bf(f0.y) << 16);
            o.y = (unsigned)f2bf(f0.z) | ((unsigned)f2bf(f0.w) << 16);
            o.z = (unsigned)f2bf(f1.x) | ((unsigned)f2bf(f1.y) << 16);
            o.w = (unsigned)f2bf(f1.z) | ((unsigned)f2bf(f1.w) << 16);
            *(uint4*)(x16 + base) = o;
        }
    }
}

// ---------------------------------------------------------------------------
// Scan: block-local exclusive scan, then per-block prefix fold
// ---------------------------------------------------------------------------
__global__ __launch_bounds__(SCAN_B) void scan1(
    const int* __restrict__ deg, int* __restrict__ rowptr, int* __restrict__ bsum)
{
    __shared__ int tmp[SCAN_B];
    int t = threadIdx.x;
    int i = blockIdx.x * SCAN_B + t;
    int v = (i < N_NODES) ? deg[i] : 0;
    tmp[t] = v;
    __syncthreads();
    for (int off = 1; off < SCAN_B; off <<= 1) {
        int u = (t >= off) ? tmp[t - off] : 0;
        __syncthreads();
        tmp[t] += u;
        __syncthreads();
    }
    if (i < N_NODES) rowptr[i] = tmp[t] - v;
    if (t == SCAN_B - 1) bsum[blockIdx.x] = tmp[t];
}

__global__ __launch_bounds__(SCAN_B) void scan23(
    int* __restrict__ rowptr, const int* __restrict__ bsum)
{
    __shared__ int red[SCAN_B];
    int t = threadIdx.x;
    int sum = 0;
    for (int i = t; i < blockIdx.x; i += SCAN_B) sum += bsum[i];
    red[t] = sum;
    __syncthreads();
    for (int off = SCAN_B / 2; off > 0; off >>= 1) {
        if (t < off) red[t] += red[t + off];
        __syncthreads();
    }
    int prefix = red[0];
    int i = blockIdx.x * SCAN_B + t;
    if (i < N_NODES) rowptr[i] += prefix;
    if (i == 0) rowptr[N_NODES] = N_EDGES;
}

// ---------------------------------------------------------------------------
// CSR fill, XCD-partitioned by dst range (kills cross-XCD partial-line
// write amplification). Stores {src*16 (uint2 index into bf16 table), attr}.
// ---------------------------------------------------------------------------
__global__ __launch_bounds__(256) void csr_fill(
    const int* __restrict__ ei, const float* __restrict__ ea,
    const int* __restrict__ rowptr, int* __restrict__ cursor,
    int2* __restrict__ csr_e)
{
    int owner = blockIdx.x & 7;
    int slice = blockIdx.x >> 3;
    int lo = owner * NODES_PER_XCD;
    int hi = lo + NODES_PER_XCD;
    int base = slice * FILL_SLICE;
    int stop = min(base + FILL_SLICE, N_EDGES);
    for (int e = base + threadIdx.x * 4; e < stop; e += 256 * 4) {
        int4 d = *(const int4*)(ei + N_EDGES + e);
        if (d.x >= lo && d.x < hi) {
            int p = rowptr[d.x] + atomicAdd(&cursor[d.x], 1);
            csr_e[p] = make_int2(ei[e + 0] << 4, __float_as_int(ea[e + 0]));
        }
        if (d.y >= lo && d.y < hi) {
            int p = rowptr[d.y] + atomicAdd(&cursor[d.y], 1);
            csr_e[p] = make_int2(ei[e + 1] << 4, __float_as_int(ea[e + 1]));
        }
        if (d.z >= lo && d.z < hi) {
            int p = rowptr[d.z] + atomicAdd(&cursor[d.z], 1);
            csr_e[p] = make_int2(ei[e + 2] << 4, __float_as_int(ea[e + 2]));
        }
        if (d.w >= lo && d.w < hi) {
            int p = rowptr[d.w] + atomicAdd(&cursor[d.w], 1);
            csr_e[p] = make_int2(ei[e + 3] << 4, __float_as_int(ea[e + 3]));
        }
    }
}

// ---------------------------------------------------------------------------
// Fused GINE layer with MFMA MLP.
// Phase 1 (gather): quarter-wave = node (32 nodes/block-iter), lane = 4 dims,
//   dwordx2 gather loads; agg -> h16 LDS tile (bf16, rows padded to 72).
// Phase 2 (MLP): wave w -> 16x16 C tile (mtile=w&1, ntile=w>>1);
//   mfma_f32_16x16x32_bf16, 2 K-steps per matmul; weights staged transposed
//   [n][k] bf16 in LDS; bias in acc init; relu between/after.
// Verified layouts: A[m=lane&15][k=quad*8+j]; C/D col=lane&15 row=quad*4+reg.
// LDS = 2*9216 (weights) + 2*4608 (h,t) = 27648 B -> 4 blocks/CU, 32 waves/CU.
// ---------------------------------------------------------------------------
template<bool SELF32, bool OUT16>
__global__ __launch_bounds__(512, 8) void gine_mfma(
    const uint2* __restrict__ g2,      // [N*16] gather table rows (bf16x4 units)
    const float* __restrict__ self32,  // [N,64] fp32 self (SELF32 only)
    const int*   __restrict__ rowptr,
    const int2*  __restrict__ csr_e,   // {src*16, attr_bits}
    const float* __restrict__ We, const float* __restrict__ be,
    const float* __restrict__ Wa, const float* __restrict__ ba,
    const float* __restrict__ Wb, const float* __restrict__ bb,
    float*        __restrict__ out32,
    unsigned int* __restrict__ out16)  // bf16x2 rows
{
    __shared__ short sWat[64 * PAD];   // Wa^T: [n][k] bf16
    __shared__ short sWbt[64 * PAD];   // Wb^T
    __shared__ short h16[32 * PAD];    // MLP input tile (bf16)
    __shared__ short t16[32 * PAD];    // hidden tile (bf16)

    int t = threadIdx.x;
    for (int i = t; i < 4096; i += 512) {        // stage weights transposed
        int k = i >> 6, n = i & 63;
        sWat[n * PAD + k] = (short)f2bf(Wa[i]);
        sWbt[n * PAD + k] = (short)f2bf(Wb[i]);
    }
    int wave = t >> 6;            // 0..7
    int lane = t & 63;
    int quad = lane >> 4;         // 0..3
    int l15  = lane & 15;
    int slot = wave * 4 + quad;   // gather node slot 0..31
    int d0   = l15 * 4;           // this lane's 4 dims (gather phase)
    float4 wp = *(const float4*)(We + d0);
    float4 bp = *(const float4*)(be + d0);
    int mtile = wave & 1;         // MFMA role
    int ntile = wave >> 1;
    int col   = ntile * 16 + l15;
    int am    = mtile * 16 + l15; // A-fragment row
    float bav = ba[col], bbv = bb[col];
    __syncthreads();

    for (int base = blockIdx.x * 32; base < N_NODES; base += gridDim.x * 32) {
        // ---- phase 1: gather ----
        int  node  = base + slot;
        bool valid = node < N_NODES;
        int beg = 0, deg = 0;
        if (valid) { beg = rowptr[node]; deg = rowptr[node + 1] - beg; }
        int dm = deg;
        dm = max(dm, __shfl_xor(dm, 16));
        dm = max(dm, __shfl_xor(dm, 32));

        float4 agg = make_float4(0.f, 0.f, 0.f, 0.f);
        #define EDGE4(rr, uu, cond)                                              \
        {                                                                        \
            float s = (cond) ? 1.f : 0.f, av = __int_as_float(rr.y);             \
            float e0 = __uint_as_float(uu.x << 16);                              \
            float e1 = __uint_as_float(uu.x & 0xFFFF0000u);                      \
            float e2 = __uint_as_float(uu.y << 16);                              \
            float e3 = __uint_as_float(uu.y & 0xFFFF0000u);                      \
            agg.x = fmaf(s, fmaxf(e0 + fmaf(av, wp.x, bp.x), 0.f), agg.x);       \
            agg.y = fmaf(s, fmaxf(e1 + fmaf(av, wp.y, bp.y), 0.f), agg.y);       \
            agg.z = fmaf(s, fmaxf(e2 + fmaf(av, wp.z, bp.z), 0.f), agg.z);       \
            agg.w = fmaf(s, fmaxf(e3 + fmaf(av, wp.w, bp.w), 0.f), agg.w);       \
        }
        for (int j = 0; j < dm; j += 4) {
            int2 r0 = csr_e[beg + ((j + 0) < deg ? j + 0 : 0)];
            int2 r1 = csr_e[beg + ((j + 1) < deg ? j + 1 : 0)];
            int2 r2 = csr_e[beg + ((j + 2) < deg ? j + 2 : 0)];
            int2 r3 = csr_e[beg + ((j + 3) < deg ? j + 3 : 0)];
            uint2 u0 = g2[r0.x + l15];
            uint2 u1 = g2[r1.x + l15];
            uint2 u2 = g2[r2.x + l15];
            uint2 u3 = g2[r3.x + l15];
            EDGE4(r0, u0, (j + 0) < deg)
            EDGE4(r1, u1, (j + 1) < deg)
            EDGE4(r2, u2, (j + 2) < deg)
            EDGE4(r3, u3, (j + 3) < deg)
        }
        #undef EDGE4
        if (valid) {   // self term (eps = 0)
            if (SELF32) {
                float4 sv = *(const float4*)(self32 + (size_t)node * DIM + d0);
                agg.x += sv.x; agg.y += sv.y; agg.z += sv.z; agg.w += sv.w;
            } else {
                uint2 u = g2[node * 16 + l15];
                agg.x += __uint_as_float(u.x << 16);
                agg.y += __uint_as_float(u.x & 0xFFFF0000u);
                agg.z += __uint_as_float(u.y << 16);
                agg.w += __uint_as_float(u.y & 0xFFFF0000u);
            }
        }
        {
            unsigned lo = (unsigned)f2bf(agg.x) | ((unsigned)f2bf(agg.y) << 16);
            unsigned hi = (unsigned)f2bf(agg.z) | ((unsigned)f2bf(agg.w) << 16);
            *(uint2*)&h16[slot * PAD + d0] = make_uint2(lo, hi);
        }
        __syncthreads();

        // ---- matmul 1: t = relu(h @ Wa + ba) ----
        f32x4 acc = {bav, bav, bav, bav};
        #pragma unroll
        for (int s = 0; s < 2; ++s) {
            bf16x8 a = *(const bf16x8*)&h16[am * PAD + s * 32 + quad * 8];
            bf16x8 b = *(const bf16x8*)&sWat[col * PAD + s * 32 + quad * 8];
            acc = __builtin_amdgcn_mfma_f32_16x16x32_bf16(a, b, acc, 0, 0, 0);
        }
        #pragma unroll
        for (int r = 0; r < 4; ++r) {
            int row = mtile * 16 + quad * 4 + r;
            t16[row * PAD + col] = (short)f2bf(fmaxf(acc[r], 0.f));
        }
        __syncthreads();

        // ---- matmul 2: h_out = relu(t @ Wb + bb) ----
        f32x4 acc2 = {bbv, bbv, bbv, bbv};
        #pragma unroll
        for (int s = 0; s < 2; ++s) {
            bf16x8 a = *(const bf16x8*)&t16[am * PAD + s * 32 + quad * 8];
            bf16x8 b = *(const bf16x8*)&sWbt[col * PAD + s * 32 + quad * 8];
            acc2 = __builtin_amdgcn_mfma_f32_16x16x32_bf16(a, b, acc2, 0, 0, 0);
        }

        if (OUT16) {
            #pragma unroll
            for (int r = 0; r < 4; ++r) {
                int row = mtile * 16 + quad * 4 + r;
                h16[row * PAD + col] = (short)f2bf(fmaxf(acc2[r], 0.f));
            }
            __syncthreads();
            int nn = t >> 4, dd = (t & 15) * 2;   // 32 nodes x 32 dwords
            if (base + nn < N_NODES) {
                uint2 v = *(const uint2*)&h16[nn * PAD + dd * 2];
                *(uint2*)&out16[(size_t)(base + nn) * 32 + dd] = v;
            }
        } else {
            #pragma unroll
            for (int r = 0; r < 4; ++r) {
                int grow = base + mtile * 16 + quad * 4 + r;
                if (grow < N_NODES)
                    out32[(size_t)grow * DIM + col] = fmaxf(acc2[r], 0.f);
            }
        }
        __syncthreads();   // protect h16/t16 for next iteration
    }
}

// ---------------------------------------------------------------------------
// Segment mean over sorted batch; one wave per graph.
// ---------------------------------------------------------------------------
__device__ __forceinline__ int lbound(const int* __restrict__ a, int key) {
    int lo = 0, hi = N_NODES;
    while (lo < hi) {
        int mid = (lo + hi) >> 1;
        if (a[mid] < key) lo = mid + 1; else hi = mid;
    }
    return lo;
}

__global__ __launch_bounds__(256) void segmean(
    const float* __restrict__ B2, const int* __restrict__ batch,
    float* __restrict__ pooled)
{
    int g   = blockIdx.x * 4 + (threadIdx.x >> 6);
    int dim = threadIdx.x & 63;
    if (g >= NUM_GRAPHS) return;
    int s = lbound(batch, g);
    int e = lbound(batch, g + 1);
    float sum = 0.f;
    int i = s;
    for (; i + 4 <= e; i += 4) {
        float v0 = B2[(size_t)(i + 0) * DIM + dim];
        float v1 = B2[(size_t)(i + 1) * DIM + dim];
        float v2 = B2[(size_t)(i + 2) * DIM + dim];
        float v3 = B2[(size_t)(i + 3) * DIM + dim];
        sum += v0 + v1 + v2 + v3;
    }
    for (; i < e; ++i) sum += B2[(size_t)i * DIM + dim];
    pooled[(size_t)g * DIM + dim] = sum / (float)max(e - s, 1);
}

// ---------------------------------------------------------------------------
// Classifier: out[g] = relu(pooled@Wc1 + bc1) @ Wc2 + bc2
// ---------------------------------------------------------------------------
__global__ __launch_bounds__(256) void classifier(
    const float* __restrict__ pooled,
    const float* __restrict__ Wc1,  const float* __restrict__ bc1,
    const float* __restrict__ Wc2,  const float* __restrict__ bc2,
    float* __restrict__ out)
{
    __shared__ float sW[64 * 64];
    __shared__ float sp[4][64];

    int t = threadIdx.x;
    for (int i = t; i < 64 * 64; i += 256) sW[i] = Wc1[i];

    int nl  = t >> 6;
    int dim = t & 63;
    int g   = blockIdx.x * 4 + nl;

    sp[nl][dim] = (g < NUM_GRAPHS) ? pooled[(size_t)g * DIM + dim] : 0.f;
    __syncthreads();

    float acc = bc1[dim];
    #pragma unroll
    for (int k = 0; k < 64; ++k)
        acc = fmaf(sp[nl][k], sW[k * 64 + dim], acc);
    float tv = fmaxf(acc, 0.f) * Wc2[dim];

    #pragma unroll
    for (int off = 32; off > 0; off >>= 1)
        tv += __shfl_down(tv, off);

    if (dim == 0 && g < NUM_GRAPHS) out[g] = tv + bc2[0];
}

extern "C" void kernel_launch(void* const* d_in, const int* in_sizes, int n_in,
                              void* d_out, int out_size, void* d_ws, size_t ws_size,
                              hipStream_t stream) {
    const float* x     = (const float*)d_in[0];
    const int*   ei    = (const int*)  d_in[1];
    const float* ea    = (const float*)d_in[2];
    const int*   batch = (const int*)  d_in[3];
    const float* W1a = (const float*)d_in[4];
    const float* b1a = (const float*)d_in[5];
    const float* W1b = (const float*)d_in[6];
    const float* b1b = (const float*)d_in[7];
    const float* We1 = (const float*)d_in[8];
    const float* be1 = (const float*)d_in[9];
    const float* W2a = (const float*)d_in[10];
    const float* b2a = (const float*)d_in[11];
    const float* W2b = (const float*)d_in[12];
    const float* b2b = (const float*)d_in[13];
    const float* We2 = (const float*)d_in[14];
    const float* be2 = (const float*)d_in[15];
    const float* Wc1 = (const float*)d_in[16];
    const float* bc1 = (const float*)d_in[17];
    const float* Wc2 = (const float*)d_in[18];
    const float* bc2 = (const float*)d_in[19];

    // workspace layout (big 16B-aligned arrays first)
    int2*           csr_e  = (int2*)d_ws;                            // [E]
    unsigned short* x16    = (unsigned short*)(csr_e + N_EDGES);     // [N*64]
    unsigned short* B16    = x16 + (size_t)N_NODES * DIM;            // [N*64]
    float*          B2     = (float*)(B16 + (size_t)N_NODES * DIM);  // [N,64]
    float*          pooled = B2 + (size_t)N_NODES * DIM;             // [G,64]
    int*            deg    = (int*)(pooled + (size_t)NUM_GRAPHS * DIM);
    int*            cursor = deg + N_NODES;
    int*            rowptr = cursor + N_NODES;                       // [N+2]
    int*            bsum   = rowptr + (N_NODES + 2);                 // [512]

    hipMemsetAsync(deg, 0, (size_t)2 * N_NODES * sizeof(int), stream);

    // ---- CSR build + bf16 table ----
    prep<<<HIST_BLK + CONV_BLK, 256, 0, stream>>>(ei, x, deg, x16);
    scan1<<<NBLK, SCAN_B, 0, stream>>>(deg, rowptr, bsum);
    scan23<<<NBLK, SCAN_B, 0, stream>>>(rowptr, bsum);
    csr_fill<<<2048, 256, 0, stream>>>(ei, ea, rowptr, cursor, csr_e);

    // ---- layer 1: gather x16, self fp32 x -> B16 (bf16) ----
    gine_mfma<true, true><<<1024, 512, 0, stream>>>(
        (const uint2*)x16, x, rowptr, csr_e,
        We1, be1, W1a, b1a, W1b, b1b, nullptr, (unsigned int*)B16);

    // ---- layer 2: gather B16 -> B2 (fp32) ----
    gine_mfma<false, false><<<1024, 512, 0, stream>>>(
        (const uint2*)B16, nullptr, rowptr, csr_e,
        We2, be2, W2a, b2a, W2b, b2b, B2, nullptr);

    // ---- pooling + classifier ----
    segmean<<<(NUM_GRAPHS + 3) / 4, 256, 0, stream>>>(B2, batch, pooled);
    classifier<<<(NUM_GRAPHS + 3) / 4, 256, 0, stream>>>(pooled, Wc1, bc1, Wc2, bc2,
                                                         (float*)d_out);
}